// Round 2
// baseline (370.710 us; speedup 1.0000x reference)
//
#include <hip/hip_runtime.h>
#include <hip/hip_bf16.h>

typedef float f32x4 __attribute__((ext_vector_type(4)));
typedef short s16x8 __attribute__((ext_vector_type(8)));

// ---- workspace layout (bytes) ----
#define OFF_EMBT   0u         // bf16 [2][2][256][512]  (embT[b][A/B][n][e])
#define OFF_W1T    1048576u   // bf16 [600][512]        (W1T[c][e])
#define OFF_W2TSW  1662976u   // bf16 swizzled [7][10][64][8]  (B-fragments of W2, padded 112x320)
#define OFF_W0BF   1734656u   // bf16 [64][512]
#define OFF_HA     1800192u   // f32 [2][4][256][320]  0=hAa+b1 1=hAb+b1 2=hBa 3=hBb
#define OFF_R2     4421632u   // f32 [2][256][256]
#define WS_TOTAL   4945920u

__device__ __forceinline__ int pack_bf2(float a, float b) {
  __hip_bfloat162 h = __float22bfloat162_rn(make_float2(a, b));
  int r; __builtin_memcpy(&r, &h, 4); return r;
}
__device__ __forceinline__ unsigned short bf16u(float f) {
  __hip_bfloat16 h = __float2bfloat16(f);
  unsigned short u; __builtin_memcpy(&u, &h, 2); return u;
}
__device__ __forceinline__ s16x8 i4_to_s8(int a, int b, int c, int d) {
  union { int i[4]; s16x8 s; } u;
  u.i[0] = a; u.i[1] = b; u.i[2] = c; u.i[3] = d; return u.s;
}

// ================= KA: pack / transpose prep =================
__global__ __launch_bounds__(256) void ka_prep(
    const float* __restrict__ act_emb, const float* __restrict__ anc_emb,
    const float* __restrict__ W1, const float* __restrict__ W2,
    const float* __restrict__ W0pn, char* __restrict__ ws)
{
  __hip_bfloat16* embT  = (__hip_bfloat16*)(ws + OFF_EMBT);
  __hip_bfloat16* W1T   = (__hip_bfloat16*)(ws + OFF_W1T);
  unsigned short* W2Tsw = (unsigned short*)(ws + OFF_W2TSW);
  unsigned short* W0bf  = (unsigned short*)(ws + OFF_W0BF);
  float*          ha_ws = (float*)(ws + OFF_HA);
  __shared__ float tile[64][65];
  int blk = blockIdx.x, t = threadIdx.x;
  if (blk < 128) {
    int b = blk >> 6, emb = (blk >> 5) & 1, ntile = (blk >> 3) & 3, etile = blk & 7;
    const float* src = emb ? anc_emb : act_emb;
    int e0 = etile * 64, n0 = ntile * 64;
    int rr = t >> 6, cc = t & 63;
    #pragma unroll
    for (int it2 = 0; it2 < 16; ++it2) {
      int e_l = rr * 16 + it2;
      tile[e_l][cc] = src[(size_t)(b * 512 + e0 + e_l) * 256 + n0 + cc];
    }
    __syncthreads();
    int n_l = t >> 2, eq = t & 3;
    unsigned int* dst = (unsigned int*)(embT + ((size_t)((b * 2 + emb) * 256 + n0 + n_l)) * 512 + e0 + eq * 16);
    #pragma unroll
    for (int kk = 0; kk < 8; ++kk)
      dst[kk] = (unsigned)pack_bf2(tile[eq * 16 + 2 * kk][n_l], tile[eq * 16 + 2 * kk + 1][n_l]);
  } else if (blk < 208) {
    int id = blk - 128;
    int half = id / 40; int rem = id % 40; int et = rem / 5; int ct = rem % 5;
    int e0 = et * 64, c0 = ct * 64;
    int rr = t >> 6, cc = t & 63;
    #pragma unroll
    for (int it2 = 0; it2 < 16; ++it2) {
      int e_l = rr * 16 + it2;
      int c = c0 + cc;
      tile[e_l][cc] = (c < 300) ? W1[(size_t)(half * 512 + e0 + e_l) * 300 + c] : 0.f;
    }
    __syncthreads();
    int c_l = t >> 2, eq = t & 3;
    if (c0 + c_l < 300) {
      unsigned int* dst = (unsigned int*)(W1T + ((size_t)(half * 300 + c0 + c_l)) * 512 + e0 + eq * 16);
      #pragma unroll
      for (int kk = 0; kk < 8; ++kk)
        dst[kk] = (unsigned)pack_bf2(tile[eq * 16 + 2 * kk][c_l], tile[eq * 16 + 2 * kk + 1][c_l]);
    }
  } else if (blk < 226) {
    int idx = (blk - 208) * 256 + t;
    if (idx < 4480) {
      int nt = idx / 640; int rem = idx - nt * 640; int ks = rem >> 6; int lane = rem & 63;
      int n = nt * 16 + (lane & 15);
      int kb = ks * 32 + (lane >> 4) * 8;
      unsigned int q[4];
      #pragma unroll
      for (int jj = 0; jj < 4; ++jj) {
        int k0 = kb + jj * 2, k1 = kb + jj * 2 + 1;
        float f0 = (n < 100 && k0 < 300) ? W2[(size_t)k0 * 100 + n] : 0.f;
        float f1 = (n < 100 && k1 < 300) ? W2[(size_t)k1 * 100 + n] : 0.f;
        q[jj] = (unsigned)pack_bf2(f0, f1);
      }
      ((uint4*)W2Tsw)[idx] = make_uint4(q[0], q[1], q[2], q[3]);
    }
  } else if (blk < 242) {
    int idx = (blk - 226) * 256 + t;
    const float* s = W0pn + (size_t)idx * 8;
    ((uint4*)W0bf)[idx] = make_uint4(
        (unsigned)pack_bf2(s[0], s[1]), (unsigned)pack_bf2(s[2], s[3]),
        (unsigned)pack_bf2(s[4], s[5]), (unsigned)pack_bf2(s[6], s[7]));
  } else {
    int base = (blk - 242) * 2560;
    f32x4 z = {0.f, 0.f, 0.f, 0.f};
    #pragma unroll
    for (int r = 0; r < 10; ++r) {
      int li = base + t + 256 * r;
      int row = li / 5, cp = li % 5;
      *(f32x4*)(ha_ws + (size_t)row * 320 + 300 + cp * 4) = z;
    }
  }
}

// ================= PointNet layer helper (runs inside k1 pn-blocks) ====
template<int K, int NT>
__device__ __forceinline__ void pn_layer(unsigned short* xb, const float* __restrict__ W,
                                         const float* __restrict__ bias, int wv, int l, int g)
{
  constexpr int NN = NT / 4;
  f32x4 z = {0.f, 0.f, 0.f, 0.f};
  f32x4 acc[NN];
  #pragma unroll
  for (int nn = 0; nn < NN; ++nn) acc[nn] = z;
  #pragma unroll
  for (int nn = 0; nn < NN; ++nn) {
    int o = (wv + nn * 4) * 16 + l;
    const float* wr0 = W + (size_t)o * K;
    #pragma unroll
    for (int ks = 0; ks < K / 32; ++ks) {
      int koff = ks * 32 + g * 8;
      f32x4 wa = *(const f32x4*)(wr0 + koff);
      f32x4 wb = *(const f32x4*)(wr0 + koff + 4);
      s16x8 bfr = i4_to_s8(pack_bf2(wa.x, wa.y), pack_bf2(wa.z, wa.w),
                           pack_bf2(wb.x, wb.y), pack_bf2(wb.z, wb.w));
      s16x8 a0 = *(const s16x8*)(xb + (size_t)l * 520 + koff);
      acc[nn] = __builtin_amdgcn_mfma_f32_16x16x32_bf16(a0, bfr, acc[nn], 0, 0, 0);
    }
  }
  __syncthreads();
  #pragma unroll
  for (int nn = 0; nn < NN; ++nn) {
    int chan = (wv + nn * 4) * 16 + l;
    float bv = bias[chan];
    #pragma unroll
    for (int r = 0; r < 4; ++r)
      xb[(size_t)(g * 4 + r) * 520 + chan] = bf16u(fmaxf(acc[nn][r] + bv, 0.f));
  }
  __syncthreads();
}

// ================= K1: hA GEMMs (blocks 0..319) + PointNet (320..351) ===
__global__ __launch_bounds__(256) void k1_ha(
    const __hip_bfloat16* __restrict__ embT, const __hip_bfloat16* __restrict__ W1T,
    const float* __restrict__ b1, float* __restrict__ ha_ws,
    const unsigned short* __restrict__ W0bf,
    const float* __restrict__ pnW1, const float* __restrict__ pnW2,
    const float* __restrict__ pnW3, const float* __restrict__ pnW4,
    const float* __restrict__ pnB0, const float* __restrict__ pnB1,
    const float* __restrict__ pnB2, const float* __restrict__ pnB3,
    const float* __restrict__ pnB4,
    const float* __restrict__ headW, float* __restrict__ out)
{
  __shared__ unsigned short xbuf[16 * 520];
  int blk = blockIdx.x, t = threadIdx.x;
  int wv = t >> 6, lane = t & 63, l = lane & 15, g = lane >> 4;
  if (blk < 320) {
    int b = blk / 160; int r = blk % 160; int emb = r / 80; r %= 80;
    int mch = r / 5; int nch = r % 5;
    int m0 = mch * 16;
    const unsigned short* Ap = (const unsigned short*)embT +
        ((size_t)((b * 2 + emb) * 256 + m0 + l)) * 512;
    const unsigned short* Wp = (const unsigned short*)W1T;
    f32x4 z = {0.f, 0.f, 0.f, 0.f};
    f32x4 acc[2] = {z, z};
    for (int ks = 0; ks < 16; ++ks) {
      int k0 = ks * 32 + g * 8;
      s16x8 af = *(const s16x8*)(Ap + k0);
      #pragma unroll
      for (int q = 0; q < 2; ++q) {
        int c = nch * 120 + (wv * 2 + q) * 16 + l;
        s16x8 bf = {0, 0, 0, 0, 0, 0, 0, 0};
        if (c < 600) bf = *(const s16x8*)(Wp + (size_t)c * 512 + k0);
        acc[q] = __builtin_amdgcn_mfma_f32_16x16x32_bf16(af, bf, acc[q], 0, 0, 0);
      }
    }
    #pragma unroll
    for (int q = 0; q < 2; ++q) {
      int cl = (wv * 2 + q) * 16 + l;
      int c = nch * 120 + cl;
      if (cl < 120 && c < 600) {
        int half = (c >= 300) ? 1 : 0;
        int cc = c - half * 300;
        float bias = (emb == 0) ? b1[cc] : 0.f;
        float* Dp = ha_ws + ((size_t)((b * 4 + emb * 2 + half) * 256 + m0 + g * 4)) * 320 + cc;
        #pragma unroll
        for (int r2 = 0; r2 < 4; ++r2)
          Dp[(size_t)r2 * 320] = acc[q][r2] + bias;
      }
    }
  } else {
    // ---- PointNet: 32 blocks, each 16 points ----
    int pn = blk - 320;
    int b_pn = pn >> 4, n0 = (pn & 15) * 16;
    unsigned short* xb = xbuf;
    {
      const unsigned short* A0 = (const unsigned short*)embT + ((size_t)(b_pn * 2 * 256 + n0)) * 512;
      f32x4 acc0 = {0.f, 0.f, 0.f, 0.f};
      int o = wv * 16 + l;
      const unsigned short* w0r = W0bf + (size_t)o * 512;
      #pragma unroll
      for (int ks = 0; ks < 16; ++ks) {
        int koff = ks * 32 + g * 8;
        s16x8 bfr = *(const s16x8*)(w0r + koff);
        s16x8 a0 = *(const s16x8*)(A0 + (size_t)l * 512 + koff);
        acc0 = __builtin_amdgcn_mfma_f32_16x16x32_bf16(a0, bfr, acc0, 0, 0, 0);
      }
      float bv = pnB0[o];
      #pragma unroll
      for (int r2 = 0; r2 < 4; ++r2)
        xb[(size_t)(g * 4 + r2) * 520 + o] = bf16u(fmaxf(acc0[r2] + bv, 0.f));
      __syncthreads();
    }
    pn_layer<64, 4>(xb, pnW1, pnB1, wv, l, g);
    pn_layer<64, 4>(xb, pnW2, pnB2, wv, l, g);
    pn_layer<64, 8>(xb, pnW3, pnB3, wv, l, g);
    pn_layer<128, 32>(xb, pnW4, pnB4, wv, l, g);
    {
      int p_l = t >> 4, os = t & 15;
      const unsigned short* row = xb + (size_t)p_l * 520 + os * 32;
      float s = 0.f;
      #pragma unroll
      for (int c = 0; c < 32; ++c) {
        unsigned int u = ((unsigned int)row[c]) << 16;
        float xv; __builtin_memcpy(&xv, &u, 4);
        s += xv * headW[os * 32 + c];
      }
      s += __shfl_xor(s, 1); s += __shfl_xor(s, 2);
      s += __shfl_xor(s, 4); s += __shfl_xor(s, 8);
      if (os == 0) out[(size_t)(b_pn * 4 + 3) * 256 + n0 + p_l] = s;
    }
  }
}

// ================= K2: pairwise MLP tail =================
// 1024 blocks: b(2) x it(16) x jt(32).  Tile = 16 i x 8 j, wave handles 2 j.
// LDS = exactly 40KB (W2 fragments nt0..3) -> 4 blocks/CU; nt4..6 via L1.
__global__ __launch_bounds__(256, 4) void k2_main(
    const float* __restrict__ ha_ws, const unsigned short* __restrict__ W2Tsw,
    const float* __restrict__ b2g, const float* __restrict__ W3g, const float* __restrict__ b3g,
    float* __restrict__ R2)
{
  __shared__ int4 w2s[2560];  // 40960 B
  int blk = blockIdx.x, t = threadIdx.x;
  int wv = t >> 6, lane = t & 63, l = lane & 15, g = lane >> 4;
  int b = blk >> 9, it = (blk >> 5) & 15, jt = blk & 31;
  int i0 = it * 16, j0 = jt * 8;
  {
    const int4* w2g = (const int4*)W2Tsw;
    for (int u = t; u < 2560; u += 256) w2s[u] = w2g[u];
  }
  __syncthreads();
  float w3v[7], b2v[7];
  #pragma unroll
  for (int nt = 0; nt < 7; ++nt) {
    int n = nt * 16 + l;
    w3v[nt] = (n < 100) ? W3g[n] : 0.f;
    b2v[nt] = (n < 100) ? b2g[n] : 0.f;
  }
  float vsum[8];
  #pragma unroll
  for (int q = 0; q < 8; ++q) vsum[q] = 0.f;
  #pragma unroll 1
  for (int rep = 0; rep < 2; ++rep) {
    const float* hap = ha_ws + ((size_t)((b * 4 + rep) * 256 + i0 + l)) * 320;
    const float* hbp = ha_ws + ((size_t)((b * 4 + (rep ? 2 : 3)) * 256 + j0 + wv * 2)) * 320;
    f32x4 z = {0.f, 0.f, 0.f, 0.f};
    f32x4 acc[2][7];
    #pragma unroll
    for (int mt = 0; mt < 2; ++mt)
      #pragma unroll
      for (int nt = 0; nt < 7; ++nt) acc[mt][nt] = z;
    for (int ks = 0; ks < 10; ++ks) {
      int koff = ks * 32 + g * 8;
      s16x8 bf[7];
      #pragma unroll
      for (int nt = 0; nt < 4; ++nt)
        bf[nt] = *(const s16x8*)&w2s[(nt * 10 + ks) * 64 + lane];
      #pragma unroll
      for (int nt = 4; nt < 7; ++nt)
        bf[nt] = *(const s16x8*)(W2Tsw + ((size_t)(nt * 10 + ks) * 64 + lane) * 8);
      f32x4 ha0 = *(const f32x4*)(hap + koff);
      f32x4 ha1 = *(const f32x4*)(hap + koff + 4);
      #pragma unroll
      for (int mt = 0; mt < 2; ++mt) {
        const float* hb = hbp + (size_t)mt * 320 + koff;
        f32x4 hb0 = *(const f32x4*)hb;
        f32x4 hb1 = *(const f32x4*)(hb + 4);
        f32x4 s0 = ha0 + hb0;
        f32x4 s1 = ha1 + hb1;
        s0 = __builtin_elementwise_max(s0, z);
        s1 = __builtin_elementwise_max(s1, z);
        s16x8 af = i4_to_s8(pack_bf2(s0.x, s0.y), pack_bf2(s0.z, s0.w),
                            pack_bf2(s1.x, s1.y), pack_bf2(s1.z, s1.w));
        #pragma unroll
        for (int nt = 0; nt < 7; ++nt)
          acc[mt][nt] = __builtin_amdgcn_mfma_f32_16x16x32_bf16(af, bf[nt], acc[mt][nt], 0, 0, 0);
      }
    }
    #pragma unroll
    for (int mt = 0; mt < 2; ++mt)
      #pragma unroll
      for (int r = 0; r < 4; ++r) {
        float pv = 0.f;
        #pragma unroll
        for (int nt = 0; nt < 7; ++nt)
          pv += fmaxf(acc[mt][nt][r] + b2v[nt], 0.f) * w3v[nt];
        vsum[mt * 4 + r] += pv;
      }
  }
  {
    float b3 = b3g[0];
    #pragma unroll
    for (int mt = 0; mt < 2; ++mt)
      #pragma unroll
      for (int r = 0; r < 4; ++r) {
        float s = vsum[mt * 4 + r];
        s += __shfl_xor(s, 1);
        s += __shfl_xor(s, 2);
        s += __shfl_xor(s, 4);
        s += __shfl_xor(s, 8);
        float S = 0.5f * s + b3;
        float Rr = (S > 20.f) ? S : log1pf(expf(S));
        if (l == 0) {
          int ii = i0 + g * 4 + r, jj2 = j0 + wv * 2 + mt;
          R2[((size_t)(b * 256 + ii)) * 256 + jj2] = Rr * Rr;
        }
      }
  }
}

// ================= K3: multilateration solve =================
__device__ __forceinline__ float block_sum(float v, float* redbuf, int t) {
  #pragma unroll
  for (int m = 1; m < 64; m <<= 1) v += __shfl_xor(v, m);
  __syncthreads();
  if ((t & 63) == 0) redbuf[t >> 6] = v;
  __syncthreads();
  return redbuf[0] + redbuf[1] + redbuf[2] + redbuf[3];
}

__global__ __launch_bounds__(256) void k3_solve(
    const float* __restrict__ anc_pts, const float* __restrict__ act_pts,
    const float* __restrict__ R2, float* __restrict__ out)
{
  __shared__ float Ax[256], Ay[256], Az[256];
  __shared__ float redbuf[4];
  int blk = blockIdx.x, t = threadIdx.x;
  int b = blk >> 2, ic = blk & 3;
  int k = t;
  float px = anc_pts[(size_t)(b * 3 + 0) * 256 + k];
  float py = anc_pts[(size_t)(b * 3 + 1) * 256 + k];
  float pz = anc_pts[(size_t)(b * 3 + 2) * 256 + k];
  float qx = block_sum(px, redbuf, t) * (1.f / 256.f);
  float qy = block_sum(py, redbuf, t) * (1.f / 256.f);
  float qz = block_sum(pz, redbuf, t) * (1.f / 256.f);
  float ax = 2.f * (px - qx), ay = 2.f * (py - qy), az = 2.f * (pz - qz);
  float p2 = px * px + py * py + pz * pz;
  Ax[k] = ax; Ay[k] = ay; Az[k] = az;
  float mxx = block_sum(ax * ax, redbuf, t);
  float mxy = block_sum(ax * ay, redbuf, t);
  float mxz = block_sum(ax * az, redbuf, t);
  float myy = block_sum(ay * ay, redbuf, t);
  float myz = block_sum(ay * az, redbuf, t);
  float mzz = block_sum(az * az, redbuf, t);
  float c0x = block_sum(ax * p2, redbuf, t);
  float c0y = block_sum(ay * p2, redbuf, t);
  float c0z = block_sum(az * p2, redbuf, t);
  __syncthreads();
  float det = mxx * (myy * mzz - myz * myz) - mxy * (mxy * mzz - myz * mxz) + mxz * (mxy * myz - myy * mxz);
  float idet = 1.f / det;
  float i00 = (myy * mzz - myz * myz) * idet;
  float i01 = (mxz * myz - mxy * mzz) * idet;
  float i02 = (mxy * myz - mxz * myy) * idet;
  float i11 = (mxx * mzz - mxz * mxz) * idet;
  float i12 = (mxy * mxz - mxx * myz) * idet;
  float i22 = (mxx * myy - mxy * mxy) * idet;
  int il = t >> 2, ks = t & 3;
  int i = ic * 64 + il;
  const float* rrow = R2 + ((size_t)(b * 256 + i)) * 256;
  float r0 = 0.f, r1 = 0.f, r2 = 0.f;
  #pragma unroll
  for (int kk = 0; kk < 16; ++kk) {
    int kb = ks * 64 + kk * 4;
    f32x4 rv = *(const f32x4*)(rrow + kb);
    r0 += Ax[kb] * rv.x + Ax[kb + 1] * rv.y + Ax[kb + 2] * rv.z + Ax[kb + 3] * rv.w;
    r1 += Ay[kb] * rv.x + Ay[kb + 1] * rv.y + Ay[kb + 2] * rv.z + Ay[kb + 3] * rv.w;
    r2 += Az[kb] * rv.x + Az[kb + 1] * rv.y + Az[kb + 2] * rv.z + Az[kb + 3] * rv.w;
  }
  r0 += __shfl_xor(r0, 1); r0 += __shfl_xor(r0, 2);
  r1 += __shfl_xor(r1, 1); r1 += __shfl_xor(r1, 2);
  r2 += __shfl_xor(r2, 1); r2 += __shfl_xor(r2, 2);
  if (ks == 0) {
    float hx = c0x - r0, hy = c0y - r1, hz = c0z - r2;
    float x0 = i00 * hx + i01 * hy + i02 * hz;
    float x1 = i01 * hx + i11 * hy + i12 * hz;
    float x2 = i02 * hx + i12 * hy + i22 * hz;
    out[(size_t)(b * 4 + 0) * 256 + i] = x0 - act_pts[(size_t)(b * 3 + 0) * 256 + i];
    out[(size_t)(b * 4 + 1) * 256 + i] = x1 - act_pts[(size_t)(b * 3 + 1) * 256 + i];
    out[(size_t)(b * 4 + 2) * 256 + i] = x2 - act_pts[(size_t)(b * 3 + 2) * 256 + i];
  }
}

extern "C" void kernel_launch(void* const* d_in, const int* in_sizes, int n_in,
                              void* d_out, int out_size, void* d_ws, size_t ws_size,
                              hipStream_t stream)
{
  const float* act_emb = (const float*)d_in[0];
  const float* anc_emb = (const float*)d_in[1];
  const float* act_pts = (const float*)d_in[2];
  const float* anc_pts = (const float*)d_in[3];
  const float* W1  = (const float*)d_in[4];
  const float* b1  = (const float*)d_in[5];
  const float* W2  = (const float*)d_in[6];
  const float* b2  = (const float*)d_in[7];
  const float* W3  = (const float*)d_in[8];
  const float* b3  = (const float*)d_in[9];
  const float* pnW0 = (const float*)d_in[10];
  const float* pnB0 = (const float*)d_in[11];
  const float* pnW1 = (const float*)d_in[12];
  const float* pnB1 = (const float*)d_in[13];
  const float* pnW2 = (const float*)d_in[14];
  const float* pnB2 = (const float*)d_in[15];
  const float* pnW3 = (const float*)d_in[16];
  const float* pnB3 = (const float*)d_in[17];
  const float* pnW4 = (const float*)d_in[18];
  const float* pnB4 = (const float*)d_in[19];
  const float* headW = (const float*)d_in[20];
  char* ws = (char*)d_ws;
  __hip_bfloat16* embT  = (__hip_bfloat16*)(ws + OFF_EMBT);
  __hip_bfloat16* W1T   = (__hip_bfloat16*)(ws + OFF_W1T);
  unsigned short* W2Tsw = (unsigned short*)(ws + OFF_W2TSW);
  unsigned short* W0bf  = (unsigned short*)(ws + OFF_W0BF);
  float* ha_ws = (float*)(ws + OFF_HA);
  float* R2ws  = (float*)(ws + OFF_R2);
  float* outp  = (float*)d_out;

  ka_prep<<<246, 256, 0, stream>>>(act_emb, anc_emb, W1, W2, pnW0, ws);
  k1_ha<<<352, 256, 0, stream>>>(embT, W1T, b1, ha_ws, W0bf,
                                 pnW1, pnW2, pnW3, pnW4, pnB0, pnB1, pnB2, pnB3, pnB4,
                                 headW, outp);
  k2_main<<<1024, 256, 0, stream>>>(ha_ws, W2Tsw, b2, W3, b3, R2ws);
  k3_solve<<<8, 256, 0, stream>>>(anc_pts, act_pts, R2ws, outp);
}

// Round 3
// 178.170 us; speedup vs baseline: 2.0807x; 2.0807x over previous
//
#include <hip/hip_runtime.h>
#include <hip/hip_bf16.h>
#include <hip/hip_fp16.h>

typedef float f32x4 __attribute__((ext_vector_type(4)));
typedef short s16x8 __attribute__((ext_vector_type(8)));
typedef _Float16 f16x8 __attribute__((ext_vector_type(8)));

// ---- workspace layout (bytes) ----
#define OFF_EMBT   0u         // bf16 [2][2][256][512]  (embT[b][A/B][n][e])
#define OFF_W1T    1048576u   // bf16 [600][512]        (W1T[c][e])
#define OFF_W2TSW  1662976u   // f16 swizzled [7][10][64][8]  (B-fragments of W2, padded 112x320)
#define OFF_W0BF   1734656u   // bf16 [64][512]
#define OFF_HA     1800192u   // f16 [2][4][256][320]  0=hAa+b1 1=hAb+b1 2=hBa 3=hBb
#define OFF_R2     3110912u   // f32 [2][256][256]
#define WS_TOTAL   3635200u

__device__ __forceinline__ int pack_bf2(float a, float b) {
  __hip_bfloat162 h = __float22bfloat162_rn(make_float2(a, b));
  int r; __builtin_memcpy(&r, &h, 4); return r;
}
__device__ __forceinline__ unsigned pack_f16_2(float a, float b) {
  __half2 h = __float22half2_rn(make_float2(a, b));
  unsigned r; __builtin_memcpy(&r, &h, 4); return r;
}
__device__ __forceinline__ unsigned short bf16u(float f) {
  __hip_bfloat16 h = __float2bfloat16(f);
  unsigned short u; __builtin_memcpy(&u, &h, 2); return u;
}
__device__ __forceinline__ s16x8 i4_to_s8(int a, int b, int c, int d) {
  union { int i[4]; s16x8 s; } u;
  u.i[0] = a; u.i[1] = b; u.i[2] = c; u.i[3] = d; return u.s;
}

// ================= KA: pack / transpose prep =================
__global__ __launch_bounds__(256) void ka_prep(
    const float* __restrict__ act_emb, const float* __restrict__ anc_emb,
    const float* __restrict__ W1, const float* __restrict__ W2,
    const float* __restrict__ W0pn, char* __restrict__ ws)
{
  __hip_bfloat16* embT  = (__hip_bfloat16*)(ws + OFF_EMBT);
  __hip_bfloat16* W1T   = (__hip_bfloat16*)(ws + OFF_W1T);
  unsigned short* W2Tsw = (unsigned short*)(ws + OFF_W2TSW);
  unsigned short* W0bf  = (unsigned short*)(ws + OFF_W0BF);
  __shared__ float tile[64][65];
  int blk = blockIdx.x, t = threadIdx.x;
  if (blk < 128) {
    int b = blk >> 6, emb = (blk >> 5) & 1, ntile = (blk >> 3) & 3, etile = blk & 7;
    const float* src = emb ? anc_emb : act_emb;
    int e0 = etile * 64, n0 = ntile * 64;
    int rr = t >> 6, cc = t & 63;
    #pragma unroll
    for (int it2 = 0; it2 < 16; ++it2) {
      int e_l = rr * 16 + it2;
      tile[e_l][cc] = src[(size_t)(b * 512 + e0 + e_l) * 256 + n0 + cc];
    }
    __syncthreads();
    int n_l = t >> 2, eq = t & 3;
    unsigned int* dst = (unsigned int*)(embT + ((size_t)((b * 2 + emb) * 256 + n0 + n_l)) * 512 + e0 + eq * 16);
    #pragma unroll
    for (int kk = 0; kk < 8; ++kk)
      dst[kk] = (unsigned)pack_bf2(tile[eq * 16 + 2 * kk][n_l], tile[eq * 16 + 2 * kk + 1][n_l]);
  } else if (blk < 208) {
    int id = blk - 128;
    int half = id / 40; int rem = id % 40; int et = rem / 5; int ct = rem % 5;
    int e0 = et * 64, c0 = ct * 64;
    int rr = t >> 6, cc = t & 63;
    #pragma unroll
    for (int it2 = 0; it2 < 16; ++it2) {
      int e_l = rr * 16 + it2;
      int c = c0 + cc;
      tile[e_l][cc] = (c < 300) ? W1[(size_t)(half * 512 + e0 + e_l) * 300 + c] : 0.f;
    }
    __syncthreads();
    int c_l = t >> 2, eq = t & 3;
    if (c0 + c_l < 300) {
      unsigned int* dst = (unsigned int*)(W1T + ((size_t)(half * 300 + c0 + c_l)) * 512 + e0 + eq * 16);
      #pragma unroll
      for (int kk = 0; kk < 8; ++kk)
        dst[kk] = (unsigned)pack_bf2(tile[eq * 16 + 2 * kk][c_l], tile[eq * 16 + 2 * kk + 1][c_l]);
    }
  } else if (blk < 226) {
    // W2 (f16) swizzled into B-fragment order: idx = (nt*10+ks)*64 + lane
    int idx = (blk - 208) * 256 + t;
    if (idx < 4480) {
      int nt = idx / 640; int rem = idx - nt * 640; int ks = rem >> 6; int lane = rem & 63;
      int n = nt * 16 + (lane & 15);
      int kb = ks * 32 + (lane >> 4) * 8;
      unsigned int q[4];
      #pragma unroll
      for (int jj = 0; jj < 4; ++jj) {
        int k0 = kb + jj * 2, k1 = kb + jj * 2 + 1;
        float f0 = (n < 100 && k0 < 300) ? W2[(size_t)k0 * 100 + n] : 0.f;
        float f1 = (n < 100 && k1 < 300) ? W2[(size_t)k1 * 100 + n] : 0.f;
        q[jj] = pack_f16_2(f0, f1);
      }
      ((uint4*)W2Tsw)[idx] = make_uint4(q[0], q[1], q[2], q[3]);
    }
  } else if (blk < 242) {
    int idx = (blk - 226) * 256 + t;
    const float* s = W0pn + (size_t)idx * 8;
    ((uint4*)W0bf)[idx] = make_uint4(
        (unsigned)pack_bf2(s[0], s[1]), (unsigned)pack_bf2(s[2], s[3]),
        (unsigned)pack_bf2(s[4], s[5]), (unsigned)pack_bf2(s[6], s[7]));
  } else {
    // zero K-pad columns [300,320) of ha_ws (f16): 2048 rows x 20 f16
    int idx = (blk - 242) * 256 + t;  // [0,1024)
    _Float16* ha = (_Float16*)(ws + OFF_HA);
    #pragma unroll
    for (int rr = 0; rr < 2; ++rr) {
      int row = idx * 2 + rr;
      unsigned* p = (unsigned*)(ha + (size_t)row * 320 + 300);
      #pragma unroll
      for (int q2 = 0; q2 < 10; ++q2) p[q2] = 0u;
    }
  }
}

// ================= PointNet layer helper (runs inside k1 pn-blocks) ====
template<int K, int NT>
__device__ __forceinline__ void pn_layer(unsigned short* xb, const float* __restrict__ W,
                                         const float* __restrict__ bias, int wv, int l, int g)
{
  constexpr int NN = NT / 4;
  f32x4 z = {0.f, 0.f, 0.f, 0.f};
  f32x4 acc[NN];
  #pragma unroll
  for (int nn = 0; nn < NN; ++nn) acc[nn] = z;
  #pragma unroll
  for (int nn = 0; nn < NN; ++nn) {
    int o = (wv + nn * 4) * 16 + l;
    const float* wr0 = W + (size_t)o * K;
    #pragma unroll
    for (int ks = 0; ks < K / 32; ++ks) {
      int koff = ks * 32 + g * 8;
      f32x4 wa = *(const f32x4*)(wr0 + koff);
      f32x4 wb = *(const f32x4*)(wr0 + koff + 4);
      s16x8 bfr = i4_to_s8(pack_bf2(wa.x, wa.y), pack_bf2(wa.z, wa.w),
                           pack_bf2(wb.x, wb.y), pack_bf2(wb.z, wb.w));
      s16x8 a0 = *(const s16x8*)(xb + (size_t)l * 520 + koff);
      acc[nn] = __builtin_amdgcn_mfma_f32_16x16x32_bf16(a0, bfr, acc[nn], 0, 0, 0);
    }
  }
  __syncthreads();
  #pragma unroll
  for (int nn = 0; nn < NN; ++nn) {
    int chan = (wv + nn * 4) * 16 + l;
    float bv = bias[chan];
    #pragma unroll
    for (int r = 0; r < 4; ++r)
      xb[(size_t)(g * 4 + r) * 520 + chan] = bf16u(fmaxf(acc[nn][r] + bv, 0.f));
  }
  __syncthreads();
}

// ================= K1: hA GEMMs (blocks 0..319) + PointNet (320..351) ===
__global__ __launch_bounds__(256) void k1_ha(
    const __hip_bfloat16* __restrict__ embT, const __hip_bfloat16* __restrict__ W1T,
    const float* __restrict__ b1, _Float16* __restrict__ ha_ws,
    const unsigned short* __restrict__ W0bf,
    const float* __restrict__ pnW1, const float* __restrict__ pnW2,
    const float* __restrict__ pnW3, const float* __restrict__ pnW4,
    const float* __restrict__ pnB0, const float* __restrict__ pnB1,
    const float* __restrict__ pnB2, const float* __restrict__ pnB3,
    const float* __restrict__ pnB4,
    const float* __restrict__ headW, float* __restrict__ out)
{
  __shared__ unsigned short xbuf[16 * 520];
  int blk = blockIdx.x, t = threadIdx.x;
  int wv = t >> 6, lane = t & 63, l = lane & 15, g = lane >> 4;
  if (blk < 320) {
    int b = blk / 160; int r = blk % 160; int emb = r / 80; r %= 80;
    int mch = r / 5; int nch = r % 5;
    int m0 = mch * 16;
    const unsigned short* Ap = (const unsigned short*)embT +
        ((size_t)((b * 2 + emb) * 256 + m0 + l)) * 512;
    const unsigned short* Wp = (const unsigned short*)W1T;
    f32x4 z = {0.f, 0.f, 0.f, 0.f};
    f32x4 acc[2] = {z, z};
    for (int ks = 0; ks < 16; ++ks) {
      int k0 = ks * 32 + g * 8;
      s16x8 af = *(const s16x8*)(Ap + k0);
      #pragma unroll
      for (int q = 0; q < 2; ++q) {
        int c = nch * 120 + (wv * 2 + q) * 16 + l;
        s16x8 bf = {0, 0, 0, 0, 0, 0, 0, 0};
        if (c < 600) bf = *(const s16x8*)(Wp + (size_t)c * 512 + k0);
        acc[q] = __builtin_amdgcn_mfma_f32_16x16x32_bf16(af, bf, acc[q], 0, 0, 0);
      }
    }
    #pragma unroll
    for (int q = 0; q < 2; ++q) {
      int cl = (wv * 2 + q) * 16 + l;
      int c = nch * 120 + cl;
      if (cl < 120 && c < 600) {
        int half = (c >= 300) ? 1 : 0;
        int cc = c - half * 300;
        float bias = (emb == 0) ? b1[cc] : 0.f;
        _Float16* Dp = ha_ws + ((size_t)((b * 4 + emb * 2 + half) * 256 + m0 + g * 4)) * 320 + cc;
        #pragma unroll
        for (int r2 = 0; r2 < 4; ++r2)
          Dp[(size_t)r2 * 320] = (_Float16)__float2half_rn(acc[q][r2] + bias);
      }
    }
  } else {
    // ---- PointNet: 32 blocks, each 16 points ----
    int pn = blk - 320;
    int b_pn = pn >> 4, n0 = (pn & 15) * 16;
    unsigned short* xb = xbuf;
    {
      const unsigned short* A0 = (const unsigned short*)embT + ((size_t)(b_pn * 2 * 256 + n0)) * 512;
      f32x4 acc0 = {0.f, 0.f, 0.f, 0.f};
      int o = wv * 16 + l;
      const unsigned short* w0r = W0bf + (size_t)o * 512;
      #pragma unroll
      for (int ks = 0; ks < 16; ++ks) {
        int koff = ks * 32 + g * 8;
        s16x8 bfr = *(const s16x8*)(w0r + koff);
        s16x8 a0 = *(const s16x8*)(A0 + (size_t)l * 512 + koff);
        acc0 = __builtin_amdgcn_mfma_f32_16x16x32_bf16(a0, bfr, acc0, 0, 0, 0);
      }
      float bv = pnB0[o];
      #pragma unroll
      for (int r2 = 0; r2 < 4; ++r2)
        xb[(size_t)(g * 4 + r2) * 520 + o] = bf16u(fmaxf(acc0[r2] + bv, 0.f));
      __syncthreads();
    }
    pn_layer<64, 4>(xb, pnW1, pnB1, wv, l, g);
    pn_layer<64, 4>(xb, pnW2, pnB2, wv, l, g);
    pn_layer<64, 8>(xb, pnW3, pnB3, wv, l, g);
    pn_layer<128, 32>(xb, pnW4, pnB4, wv, l, g);
    {
      int p_l = t >> 4, os = t & 15;
      const unsigned short* row = xb + (size_t)p_l * 520 + os * 32;
      float s = 0.f;
      #pragma unroll
      for (int c = 0; c < 32; ++c) {
        unsigned int u = ((unsigned int)row[c]) << 16;
        float xv; __builtin_memcpy(&xv, &u, 4);
        s += xv * headW[os * 32 + c];
      }
      s += __shfl_xor(s, 1); s += __shfl_xor(s, 2);
      s += __shfl_xor(s, 4); s += __shfl_xor(s, 8);
      if (os == 0) out[(size_t)(b_pn * 4 + 3) * 256 + n0 + p_l] = s;
    }
  }
}

// ================= K2: pairwise MLP tail (f16, rep-fused) =================
// 2048 blocks: b(2) x it(16) x jt(64). Tile = 16 i x 4 j; each wave owns 1 j.
// Both reps accumulated in one k-loop (W2 fragments shared).
// LDS = 51.2KB (W2 nt0..4); nt5,6 from global (20KB, L1-resident).
__global__ __launch_bounds__(256, 3) void k2_main(
    const _Float16* __restrict__ ha_ws, const unsigned short* __restrict__ W2Tsw,
    const float* __restrict__ b2g, const float* __restrict__ W3g, const float* __restrict__ b3g,
    float* __restrict__ R2)
{
  __shared__ int4 w2s[3200];  // 51200 B : nt 0..4
  int blk = blockIdx.x, t = threadIdx.x;
  int wv = t >> 6, lane = t & 63, l = lane & 15, g = lane >> 4;
  int b = blk >> 10, it = (blk >> 6) & 15, jt = blk & 63;
  int i0 = it * 16, j = jt * 4 + wv;
  {
    const int4* w2g = (const int4*)W2Tsw;
    for (int u = t; u < 3200; u += 256) w2s[u] = w2g[u];
  }
  __syncthreads();
  float w3v[7], b2v[7];
  #pragma unroll
  for (int nt = 0; nt < 7; ++nt) {
    int n = nt * 16 + l;
    w3v[nt] = (n < 100) ? W3g[n] : 0.f;
    b2v[nt] = (n < 100) ? b2g[n] : 0.f;
  }
  // rep0: A = relu(hAa[i]+b1 + hBb[j]);  rep1: A = relu(hAb[i]+b1 + hBa[j])
  const _Float16* hap0 = ha_ws + ((size_t)((b * 4 + 0) * 256 + i0 + l)) * 320;
  const _Float16* hap1 = ha_ws + ((size_t)((b * 4 + 1) * 256 + i0 + l)) * 320;
  const _Float16* hbp0 = ha_ws + ((size_t)((b * 4 + 3) * 256 + j)) * 320;
  const _Float16* hbp1 = ha_ws + ((size_t)((b * 4 + 2) * 256 + j)) * 320;
  f32x4 z = {0.f, 0.f, 0.f, 0.f};
  f32x4 acc0[7], acc1[7];
  #pragma unroll
  for (int nt = 0; nt < 7; ++nt) { acc0[nt] = z; acc1[nt] = z; }
  const f16x8 zf = {0, 0, 0, 0, 0, 0, 0, 0};
  #pragma unroll
  for (int ks = 0; ks < 10; ++ks) {
    int koff = ks * 32 + g * 8;
    f16x8 bf[7];
    #pragma unroll
    for (int nt = 0; nt < 5; ++nt)
      bf[nt] = *(const f16x8*)&w2s[(nt * 10 + ks) * 64 + lane];
    #pragma unroll
    for (int nt = 5; nt < 7; ++nt)
      bf[nt] = *(const f16x8*)(W2Tsw + ((size_t)(nt * 10 + ks) * 64 + lane) * 8);
    f16x8 ha0 = *(const f16x8*)(hap0 + koff);
    f16x8 hb0 = *(const f16x8*)(hbp0 + koff);
    f16x8 ha1 = *(const f16x8*)(hap1 + koff);
    f16x8 hb1 = *(const f16x8*)(hbp1 + koff);
    f16x8 af0 = __builtin_elementwise_max(ha0 + hb0, zf);
    f16x8 af1 = __builtin_elementwise_max(ha1 + hb1, zf);
    #pragma unroll
    for (int nt = 0; nt < 7; ++nt) {
      acc0[nt] = __builtin_amdgcn_mfma_f32_16x16x32_f16(af0, bf[nt], acc0[nt], 0, 0, 0);
      acc1[nt] = __builtin_amdgcn_mfma_f32_16x16x32_f16(af1, bf[nt], acc1[nt], 0, 0, 0);
    }
  }
  {
    float b3 = b3g[0];
    #pragma unroll
    for (int r = 0; r < 4; ++r) {
      float pv = 0.f;
      #pragma unroll
      for (int nt = 0; nt < 7; ++nt) {
        pv += fmaxf(acc0[nt][r] + b2v[nt], 0.f) * w3v[nt];
        pv += fmaxf(acc1[nt][r] + b2v[nt], 0.f) * w3v[nt];
      }
      pv += __shfl_xor(pv, 1);
      pv += __shfl_xor(pv, 2);
      pv += __shfl_xor(pv, 4);
      pv += __shfl_xor(pv, 8);
      float S = 0.5f * pv + b3;
      float Rr = (S > 20.f) ? S : log1pf(expf(S));
      if (l == 0)
        R2[((size_t)(b * 256 + i0 + g * 4 + r)) * 256 + j] = Rr * Rr;
    }
  }
}

// ================= K3: multilateration solve =================
__device__ __forceinline__ float block_sum(float v, float* redbuf, int t) {
  #pragma unroll
  for (int m = 1; m < 64; m <<= 1) v += __shfl_xor(v, m);
  __syncthreads();
  if ((t & 63) == 0) redbuf[t >> 6] = v;
  __syncthreads();
  return redbuf[0] + redbuf[1] + redbuf[2] + redbuf[3];
}

__global__ __launch_bounds__(256) void k3_solve(
    const float* __restrict__ anc_pts, const float* __restrict__ act_pts,
    const float* __restrict__ R2, float* __restrict__ out)
{
  __shared__ float Ax[256], Ay[256], Az[256];
  __shared__ float redbuf[4];
  int blk = blockIdx.x, t = threadIdx.x;
  int b = blk >> 2, ic = blk & 3;
  int k = t;
  float px = anc_pts[(size_t)(b * 3 + 0) * 256 + k];
  float py = anc_pts[(size_t)(b * 3 + 1) * 256 + k];
  float pz = anc_pts[(size_t)(b * 3 + 2) * 256 + k];
  float qx = block_sum(px, redbuf, t) * (1.f / 256.f);
  float qy = block_sum(py, redbuf, t) * (1.f / 256.f);
  float qz = block_sum(pz, redbuf, t) * (1.f / 256.f);
  float ax = 2.f * (px - qx), ay = 2.f * (py - qy), az = 2.f * (pz - qz);
  float p2 = px * px + py * py + pz * pz;
  Ax[k] = ax; Ay[k] = ay; Az[k] = az;
  float mxx = block_sum(ax * ax, redbuf, t);
  float mxy = block_sum(ax * ay, redbuf, t);
  float mxz = block_sum(ax * az, redbuf, t);
  float myy = block_sum(ay * ay, redbuf, t);
  float myz = block_sum(ay * az, redbuf, t);
  float mzz = block_sum(az * az, redbuf, t);
  float c0x = block_sum(ax * p2, redbuf, t);
  float c0y = block_sum(ay * p2, redbuf, t);
  float c0z = block_sum(az * p2, redbuf, t);
  __syncthreads();
  float det = mxx * (myy * mzz - myz * myz) - mxy * (mxy * mzz - myz * mxz) + mxz * (mxy * myz - myy * mxz);
  float idet = 1.f / det;
  float i00 = (myy * mzz - myz * myz) * idet;
  float i01 = (mxz * myz - mxy * mzz) * idet;
  float i02 = (mxy * myz - mxz * myy) * idet;
  float i11 = (mxx * mzz - mxz * mxz) * idet;
  float i12 = (mxy * mxz - mxx * myz) * idet;
  float i22 = (mxx * myy - mxy * mxy) * idet;
  int il = t >> 2, ks = t & 3;
  int i = ic * 64 + il;
  const float* rrow = R2 + ((size_t)(b * 256 + i)) * 256;
  float r0 = 0.f, r1 = 0.f, r2 = 0.f;
  #pragma unroll
  for (int kk = 0; kk < 16; ++kk) {
    int kb = ks * 64 + kk * 4;
    f32x4 rv = *(const f32x4*)(rrow + kb);
    r0 += Ax[kb] * rv.x + Ax[kb + 1] * rv.y + Ax[kb + 2] * rv.z + Ax[kb + 3] * rv.w;
    r1 += Ay[kb] * rv.x + Ay[kb + 1] * rv.y + Ay[kb + 2] * rv.z + Ay[kb + 3] * rv.w;
    r2 += Az[kb] * rv.x + Az[kb + 1] * rv.y + Az[kb + 2] * rv.z + Az[kb + 3] * rv.w;
  }
  r0 += __shfl_xor(r0, 1); r0 += __shfl_xor(r0, 2);
  r1 += __shfl_xor(r1, 1); r1 += __shfl_xor(r1, 2);
  r2 += __shfl_xor(r2, 1); r2 += __shfl_xor(r2, 2);
  if (ks == 0) {
    float hx = c0x - r0, hy = c0y - r1, hz = c0z - r2;
    float x0 = i00 * hx + i01 * hy + i02 * hz;
    float x1 = i01 * hx + i11 * hy + i12 * hz;
    float x2 = i02 * hx + i12 * hy + i22 * hz;
    out[(size_t)(b * 4 + 0) * 256 + i] = x0 - act_pts[(size_t)(b * 3 + 0) * 256 + i];
    out[(size_t)(b * 4 + 1) * 256 + i] = x1 - act_pts[(size_t)(b * 3 + 1) * 256 + i];
    out[(size_t)(b * 4 + 2) * 256 + i] = x2 - act_pts[(size_t)(b * 3 + 2) * 256 + i];
  }
}

extern "C" void kernel_launch(void* const* d_in, const int* in_sizes, int n_in,
                              void* d_out, int out_size, void* d_ws, size_t ws_size,
                              hipStream_t stream)
{
  const float* act_emb = (const float*)d_in[0];
  const float* anc_emb = (const float*)d_in[1];
  const float* act_pts = (const float*)d_in[2];
  const float* anc_pts = (const float*)d_in[3];
  const float* W1  = (const float*)d_in[4];
  const float* b1  = (const float*)d_in[5];
  const float* W2  = (const float*)d_in[6];
  const float* b2  = (const float*)d_in[7];
  const float* W3  = (const float*)d_in[8];
  const float* b3  = (const float*)d_in[9];
  const float* pnW0 = (const float*)d_in[10];
  const float* pnB0 = (const float*)d_in[11];
  const float* pnW1 = (const float*)d_in[12];
  const float* pnB1 = (const float*)d_in[13];
  const float* pnW2 = (const float*)d_in[14];
  const float* pnB2 = (const float*)d_in[15];
  const float* pnW3 = (const float*)d_in[16];
  const float* pnB3 = (const float*)d_in[17];
  const float* pnW4 = (const float*)d_in[18];
  const float* pnB4 = (const float*)d_in[19];
  const float* headW = (const float*)d_in[20];
  char* ws = (char*)d_ws;
  __hip_bfloat16* embT  = (__hip_bfloat16*)(ws + OFF_EMBT);
  __hip_bfloat16* W1T   = (__hip_bfloat16*)(ws + OFF_W1T);
  unsigned short* W2Tsw = (unsigned short*)(ws + OFF_W2TSW);
  unsigned short* W0bf  = (unsigned short*)(ws + OFF_W0BF);
  _Float16* ha_ws = (_Float16*)(ws + OFF_HA);
  float* R2ws  = (float*)(ws + OFF_R2);
  float* outp  = (float*)d_out;

  ka_prep<<<246, 256, 0, stream>>>(act_emb, anc_emb, W1, W2, pnW0, ws);
  k1_ha<<<352, 256, 0, stream>>>(embT, W1T, b1, ha_ws, W0bf,
                                 pnW1, pnW2, pnW3, pnW4, pnB0, pnB1, pnB2, pnB3, pnB4,
                                 headW, outp);
  k2_main<<<2048, 256, 0, stream>>>(ha_ws, W2Tsw, b2, W3, b3, R2ws);
  k3_solve<<<8, 256, 0, stream>>>(anc_pts, act_pts, R2ws, outp);
}

// Round 4
// 177.159 us; speedup vs baseline: 2.0925x; 1.0057x over previous
//
#include <hip/hip_runtime.h>
#include <hip/hip_bf16.h>
#include <hip/hip_fp16.h>

typedef float f32x4 __attribute__((ext_vector_type(4)));
typedef short s16x8 __attribute__((ext_vector_type(8)));
typedef _Float16 f16x8 __attribute__((ext_vector_type(8)));

// ---- workspace layout (bytes) ----
#define OFF_EMBT   0u         // bf16 [2][2][256][512]  (embT[b][A/B][n][e])
#define OFF_W1T    1048576u   // bf16 [600][512]        (W1T[c][e])
#define OFF_W2TSW  1662976u   // f16 swizzled [7][10][64][8]  (B-fragments of W2, padded 112x320)
#define OFF_W0BF   1734656u   // bf16 [64][512]
#define OFF_HA     1800192u   // f16 [2][4][256][320]  0=hAa+b1 1=hAb+b1 2=hBa 3=hBb
#define OFF_R2     3110912u   // f32 [2][256][256]
#define WS_TOTAL   3635200u

__device__ __forceinline__ int pack_bf2(float a, float b) {
  __hip_bfloat162 h = __float22bfloat162_rn(make_float2(a, b));
  int r; __builtin_memcpy(&r, &h, 4); return r;
}
__device__ __forceinline__ unsigned pack_f16_2(float a, float b) {
  __half2 h = __float22half2_rn(make_float2(a, b));
  unsigned r; __builtin_memcpy(&r, &h, 4); return r;
}
__device__ __forceinline__ unsigned short bf16u(float f) {
  __hip_bfloat16 h = __float2bfloat16(f);
  unsigned short u; __builtin_memcpy(&u, &h, 2); return u;
}
__device__ __forceinline__ s16x8 i4_to_s8(int a, int b, int c, int d) {
  union { int i[4]; s16x8 s; } u;
  u.i[0] = a; u.i[1] = b; u.i[2] = c; u.i[3] = d; return u.s;
}

// ================= KA: pack / transpose prep =================
__global__ __launch_bounds__(256) void ka_prep(
    const float* __restrict__ act_emb, const float* __restrict__ anc_emb,
    const float* __restrict__ W1, const float* __restrict__ W2,
    const float* __restrict__ W0pn, char* __restrict__ ws)
{
  __hip_bfloat16* embT  = (__hip_bfloat16*)(ws + OFF_EMBT);
  __hip_bfloat16* W1T   = (__hip_bfloat16*)(ws + OFF_W1T);
  unsigned short* W2Tsw = (unsigned short*)(ws + OFF_W2TSW);
  unsigned short* W0bf  = (unsigned short*)(ws + OFF_W0BF);
  __shared__ float tile[64][65];
  int blk = blockIdx.x, t = threadIdx.x;
  if (blk < 128) {
    int b = blk >> 6, emb = (blk >> 5) & 1, ntile = (blk >> 3) & 3, etile = blk & 7;
    const float* src = emb ? anc_emb : act_emb;
    int e0 = etile * 64, n0 = ntile * 64;
    int rr = t >> 6, cc = t & 63;
    #pragma unroll
    for (int it2 = 0; it2 < 16; ++it2) {
      int e_l = rr * 16 + it2;
      tile[e_l][cc] = src[(size_t)(b * 512 + e0 + e_l) * 256 + n0 + cc];
    }
    __syncthreads();
    int n_l = t >> 2, eq = t & 3;
    unsigned int* dst = (unsigned int*)(embT + ((size_t)((b * 2 + emb) * 256 + n0 + n_l)) * 512 + e0 + eq * 16);
    #pragma unroll
    for (int kk = 0; kk < 8; ++kk)
      dst[kk] = (unsigned)pack_bf2(tile[eq * 16 + 2 * kk][n_l], tile[eq * 16 + 2 * kk + 1][n_l]);
  } else if (blk < 208) {
    int id = blk - 128;
    int half = id / 40; int rem = id % 40; int et = rem / 5; int ct = rem % 5;
    int e0 = et * 64, c0 = ct * 64;
    int rr = t >> 6, cc = t & 63;
    #pragma unroll
    for (int it2 = 0; it2 < 16; ++it2) {
      int e_l = rr * 16 + it2;
      int c = c0 + cc;
      tile[e_l][cc] = (c < 300) ? W1[(size_t)(half * 512 + e0 + e_l) * 300 + c] : 0.f;
    }
    __syncthreads();
    int c_l = t >> 2, eq = t & 3;
    if (c0 + c_l < 300) {
      unsigned int* dst = (unsigned int*)(W1T + ((size_t)(half * 300 + c0 + c_l)) * 512 + e0 + eq * 16);
      #pragma unroll
      for (int kk = 0; kk < 8; ++kk)
        dst[kk] = (unsigned)pack_bf2(tile[eq * 16 + 2 * kk][c_l], tile[eq * 16 + 2 * kk + 1][c_l]);
    }
  } else if (blk < 226) {
    // W2 (f16) swizzled into B-fragment order: idx = (nt*10+ks)*64 + lane
    int idx = (blk - 208) * 256 + t;
    if (idx < 4480) {
      int nt = idx / 640; int rem = idx - nt * 640; int ks = rem >> 6; int lane = rem & 63;
      int n = nt * 16 + (lane & 15);
      int kb = ks * 32 + (lane >> 4) * 8;
      unsigned int q[4];
      #pragma unroll
      for (int jj = 0; jj < 4; ++jj) {
        int k0 = kb + jj * 2, k1 = kb + jj * 2 + 1;
        float f0 = (n < 100 && k0 < 300) ? W2[(size_t)k0 * 100 + n] : 0.f;
        float f1 = (n < 100 && k1 < 300) ? W2[(size_t)k1 * 100 + n] : 0.f;
        q[jj] = pack_f16_2(f0, f1);
      }
      ((uint4*)W2Tsw)[idx] = make_uint4(q[0], q[1], q[2], q[3]);
    }
  } else if (blk < 242) {
    int idx = (blk - 226) * 256 + t;
    const float* s = W0pn + (size_t)idx * 8;
    ((uint4*)W0bf)[idx] = make_uint4(
        (unsigned)pack_bf2(s[0], s[1]), (unsigned)pack_bf2(s[2], s[3]),
        (unsigned)pack_bf2(s[4], s[5]), (unsigned)pack_bf2(s[6], s[7]));
  } else {
    // zero K-pad columns [300,320) of ha_ws (f16): 2048 rows x 20 f16
    int idx = (blk - 242) * 256 + t;  // [0,1024)
    _Float16* ha = (_Float16*)(ws + OFF_HA);
    #pragma unroll
    for (int rr = 0; rr < 2; ++rr) {
      int row = idx * 2 + rr;
      unsigned* p = (unsigned*)(ha + (size_t)row * 320 + 300);
      #pragma unroll
      for (int q2 = 0; q2 < 10; ++q2) p[q2] = 0u;
    }
  }
}

// ================= PointNet layer helper (runs inside k1 pn-blocks) ====
template<int K, int NT>
__device__ __forceinline__ void pn_layer(unsigned short* xb, const float* __restrict__ W,
                                         const float* __restrict__ bias, int wv, int l, int g)
{
  constexpr int NN = NT / 4;
  f32x4 z = {0.f, 0.f, 0.f, 0.f};
  f32x4 acc[NN];
  #pragma unroll
  for (int nn = 0; nn < NN; ++nn) acc[nn] = z;
  #pragma unroll
  for (int nn = 0; nn < NN; ++nn) {
    int o = (wv + nn * 4) * 16 + l;
    const float* wr0 = W + (size_t)o * K;
    #pragma unroll
    for (int ks = 0; ks < K / 32; ++ks) {
      int koff = ks * 32 + g * 8;
      f32x4 wa = *(const f32x4*)(wr0 + koff);
      f32x4 wb = *(const f32x4*)(wr0 + koff + 4);
      s16x8 bfr = i4_to_s8(pack_bf2(wa.x, wa.y), pack_bf2(wa.z, wa.w),
                           pack_bf2(wb.x, wb.y), pack_bf2(wb.z, wb.w));
      s16x8 a0 = *(const s16x8*)(xb + (size_t)l * 520 + koff);
      acc[nn] = __builtin_amdgcn_mfma_f32_16x16x32_bf16(a0, bfr, acc[nn], 0, 0, 0);
    }
  }
  __syncthreads();
  #pragma unroll
  for (int nn = 0; nn < NN; ++nn) {
    int chan = (wv + nn * 4) * 16 + l;
    float bv = bias[chan];
    #pragma unroll
    for (int r = 0; r < 4; ++r)
      xb[(size_t)(g * 4 + r) * 520 + chan] = bf16u(fmaxf(acc[nn][r] + bv, 0.f));
  }
  __syncthreads();
}

// ================= K1: hA GEMMs (blocks 0..319) + PointNet (320..351) ===
__global__ __launch_bounds__(256) void k1_ha(
    const __hip_bfloat16* __restrict__ embT, const __hip_bfloat16* __restrict__ W1T,
    const float* __restrict__ b1, _Float16* __restrict__ ha_ws,
    const unsigned short* __restrict__ W0bf,
    const float* __restrict__ pnW1, const float* __restrict__ pnW2,
    const float* __restrict__ pnW3, const float* __restrict__ pnW4,
    const float* __restrict__ pnB0, const float* __restrict__ pnB1,
    const float* __restrict__ pnB2, const float* __restrict__ pnB3,
    const float* __restrict__ pnB4,
    const float* __restrict__ headW, float* __restrict__ out)
{
  __shared__ unsigned short xbuf[16 * 520];
  int blk = blockIdx.x, t = threadIdx.x;
  int wv = t >> 6, lane = t & 63, l = lane & 15, g = lane >> 4;
  if (blk < 320) {
    int b = blk / 160; int r = blk % 160; int emb = r / 80; r %= 80;
    int mch = r / 5; int nch = r % 5;
    int m0 = mch * 16;
    const unsigned short* Ap = (const unsigned short*)embT +
        ((size_t)((b * 2 + emb) * 256 + m0 + l)) * 512;
    const unsigned short* Wp = (const unsigned short*)W1T;
    f32x4 z = {0.f, 0.f, 0.f, 0.f};
    f32x4 acc[2] = {z, z};
    for (int ks = 0; ks < 16; ++ks) {
      int k0 = ks * 32 + g * 8;
      s16x8 af = *(const s16x8*)(Ap + k0);
      #pragma unroll
      for (int q = 0; q < 2; ++q) {
        int c = nch * 120 + (wv * 2 + q) * 16 + l;
        s16x8 bf = {0, 0, 0, 0, 0, 0, 0, 0};
        if (c < 600) bf = *(const s16x8*)(Wp + (size_t)c * 512 + k0);
        acc[q] = __builtin_amdgcn_mfma_f32_16x16x32_bf16(af, bf, acc[q], 0, 0, 0);
      }
    }
    #pragma unroll
    for (int q = 0; q < 2; ++q) {
      int cl = (wv * 2 + q) * 16 + l;
      int c = nch * 120 + cl;
      if (cl < 120 && c < 600) {
        int half = (c >= 300) ? 1 : 0;
        int cc = c - half * 300;
        float bias = (emb == 0) ? b1[cc] : 0.f;
        _Float16* Dp = ha_ws + ((size_t)((b * 4 + emb * 2 + half) * 256 + m0 + g * 4)) * 320 + cc;
        #pragma unroll
        for (int r2 = 0; r2 < 4; ++r2)
          Dp[(size_t)r2 * 320] = (_Float16)__float2half_rn(acc[q][r2] + bias);
      }
    }
  } else {
    // ---- PointNet: 32 blocks, each 16 points ----
    int pn = blk - 320;
    int b_pn = pn >> 4, n0 = (pn & 15) * 16;
    unsigned short* xb = xbuf;
    {
      const unsigned short* A0 = (const unsigned short*)embT + ((size_t)(b_pn * 2 * 256 + n0)) * 512;
      f32x4 acc0 = {0.f, 0.f, 0.f, 0.f};
      int o = wv * 16 + l;
      const unsigned short* w0r = W0bf + (size_t)o * 512;
      #pragma unroll
      for (int ks = 0; ks < 16; ++ks) {
        int koff = ks * 32 + g * 8;
        s16x8 bfr = *(const s16x8*)(w0r + koff);
        s16x8 a0 = *(const s16x8*)(A0 + (size_t)l * 512 + koff);
        acc0 = __builtin_amdgcn_mfma_f32_16x16x32_bf16(a0, bfr, acc0, 0, 0, 0);
      }
      float bv = pnB0[o];
      #pragma unroll
      for (int r2 = 0; r2 < 4; ++r2)
        xb[(size_t)(g * 4 + r2) * 520 + o] = bf16u(fmaxf(acc0[r2] + bv, 0.f));
      __syncthreads();
    }
    pn_layer<64, 4>(xb, pnW1, pnB1, wv, l, g);
    pn_layer<64, 4>(xb, pnW2, pnB2, wv, l, g);
    pn_layer<64, 8>(xb, pnW3, pnB3, wv, l, g);
    pn_layer<128, 32>(xb, pnW4, pnB4, wv, l, g);
    {
      int p_l = t >> 4, os = t & 15;
      const unsigned short* row = xb + (size_t)p_l * 520 + os * 32;
      float s = 0.f;
      #pragma unroll
      for (int c = 0; c < 32; ++c) {
        unsigned int u = ((unsigned int)row[c]) << 16;
        float xv; __builtin_memcpy(&xv, &u, 4);
        s += xv * headW[os * 32 + c];
      }
      s += __shfl_xor(s, 1); s += __shfl_xor(s, 2);
      s += __shfl_xor(s, 4); s += __shfl_xor(s, 8);
      if (os == 0) out[(size_t)(b_pn * 4 + 3) * 256 + n0 + p_l] = s;
    }
  }
}

// ================= K2: pairwise MLP tail (f16, hb-in-registers) ==========
// 2048 blocks: b(2) x it(16) x jt(64). Tile = 16 i x 4 j; each wave owns 1 j.
// hb rows (wave-private) preloaded into 80 VGPRs -> only 2 global loads/ks.
// All 7 W2 nt-tiles staged in LDS (71680 B) -> 2 blocks/CU, reg cap 256.
__global__ __launch_bounds__(256, 2) void k2_main(
    const _Float16* __restrict__ ha_ws, const unsigned short* __restrict__ W2Tsw,
    const float* __restrict__ b2g, const float* __restrict__ W3g, const float* __restrict__ b3g,
    float* __restrict__ R2)
{
  __shared__ int4 w2s[4480];  // 71680 B : all 7 nt
  int blk = blockIdx.x, t = threadIdx.x;
  int wv = t >> 6, lane = t & 63, l = lane & 15, g = lane >> 4;
  int b = blk >> 10, it = (blk >> 6) & 15, jt = blk & 63;
  int i0 = it * 16, j = jt * 4 + wv;
  // preload hb rows for this wave's j (independent of LDS staging)
  const _Float16* hbp0 = ha_ws + ((size_t)((b * 4 + 3) * 256 + j)) * 320;  // hBb (rep0)
  const _Float16* hbp1 = ha_ws + ((size_t)((b * 4 + 2) * 256 + j)) * 320;  // hBa (rep1)
  f16x8 hb0r[10], hb1r[10];
  #pragma unroll
  for (int ks = 0; ks < 10; ++ks) {
    hb0r[ks] = *(const f16x8*)(hbp0 + ks * 32 + g * 8);
    hb1r[ks] = *(const f16x8*)(hbp1 + ks * 32 + g * 8);
  }
  // stage all W2 fragments into LDS
  {
    const int4* w2g = (const int4*)W2Tsw;
    for (int u = t; u < 4480; u += 256) w2s[u] = w2g[u];
  }
  __syncthreads();
  const _Float16* hap0 = ha_ws + ((size_t)((b * 4 + 0) * 256 + i0 + l)) * 320;  // hAa+b1
  const _Float16* hap1 = ha_ws + ((size_t)((b * 4 + 1) * 256 + i0 + l)) * 320;  // hAb+b1
  f32x4 z = {0.f, 0.f, 0.f, 0.f};
  f32x4 acc0[7], acc1[7];
  #pragma unroll
  for (int nt = 0; nt < 7; ++nt) { acc0[nt] = z; acc1[nt] = z; }
  const f16x8 zf = {0, 0, 0, 0, 0, 0, 0, 0};
  #pragma unroll
  for (int ks = 0; ks < 10; ++ks) {
    f16x8 ha0 = *(const f16x8*)(hap0 + ks * 32 + g * 8);
    f16x8 ha1 = *(const f16x8*)(hap1 + ks * 32 + g * 8);
    f16x8 af0 = __builtin_elementwise_max(ha0 + hb0r[ks], zf);
    f16x8 af1 = __builtin_elementwise_max(ha1 + hb1r[ks], zf);
    #pragma unroll
    for (int nt = 0; nt < 7; ++nt) {
      f16x8 bf = *(const f16x8*)&w2s[(nt * 10 + ks) * 64 + lane];
      acc0[nt] = __builtin_amdgcn_mfma_f32_16x16x32_f16(af0, bf, acc0[nt], 0, 0, 0);
      acc1[nt] = __builtin_amdgcn_mfma_f32_16x16x32_f16(af1, bf, acc1[nt], 0, 0, 0);
    }
  }
  // epilogue: relu(h2)+dot(W3), reduce over the 16-lane col group, softplus
  {
    float w3v[7], b2v[7];
    #pragma unroll
    for (int nt = 0; nt < 7; ++nt) {
      int n = nt * 16 + l;
      w3v[nt] = (n < 100) ? W3g[n] : 0.f;
      b2v[nt] = (n < 100) ? b2g[n] : 0.f;
    }
    float b3 = b3g[0];
    #pragma unroll
    for (int r = 0; r < 4; ++r) {
      float pv = 0.f;
      #pragma unroll
      for (int nt = 0; nt < 7; ++nt) {
        pv += fmaxf(acc0[nt][r] + b2v[nt], 0.f) * w3v[nt];
        pv += fmaxf(acc1[nt][r] + b2v[nt], 0.f) * w3v[nt];
      }
      pv += __shfl_xor(pv, 1);
      pv += __shfl_xor(pv, 2);
      pv += __shfl_xor(pv, 4);
      pv += __shfl_xor(pv, 8);
      float S = 0.5f * pv + b3;
      float Rr = (S > 20.f) ? S : log1pf(expf(S));
      if (l == 0)
        R2[((size_t)(b * 256 + i0 + g * 4 + r)) * 256 + j] = Rr * Rr;
    }
  }
}

// ================= K3: multilateration solve =================
__device__ __forceinline__ float block_sum(float v, float* redbuf, int t) {
  #pragma unroll
  for (int m = 1; m < 64; m <<= 1) v += __shfl_xor(v, m);
  __syncthreads();
  if ((t & 63) == 0) redbuf[t >> 6] = v;
  __syncthreads();
  return redbuf[0] + redbuf[1] + redbuf[2] + redbuf[3];
}

__global__ __launch_bounds__(256) void k3_solve(
    const float* __restrict__ anc_pts, const float* __restrict__ act_pts,
    const float* __restrict__ R2, float* __restrict__ out)
{
  __shared__ float Ax[256], Ay[256], Az[256];
  __shared__ float redbuf[4];
  int blk = blockIdx.x, t = threadIdx.x;
  int b = blk >> 2, ic = blk & 3;
  int k = t;
  float px = anc_pts[(size_t)(b * 3 + 0) * 256 + k];
  float py = anc_pts[(size_t)(b * 3 + 1) * 256 + k];
  float pz = anc_pts[(size_t)(b * 3 + 2) * 256 + k];
  float qx = block_sum(px, redbuf, t) * (1.f / 256.f);
  float qy = block_sum(py, redbuf, t) * (1.f / 256.f);
  float qz = block_sum(pz, redbuf, t) * (1.f / 256.f);
  float ax = 2.f * (px - qx), ay = 2.f * (py - qy), az = 2.f * (pz - qz);
  float p2 = px * px + py * py + pz * pz;
  Ax[k] = ax; Ay[k] = ay; Az[k] = az;
  float mxx = block_sum(ax * ax, redbuf, t);
  float mxy = block_sum(ax * ay, redbuf, t);
  float mxz = block_sum(ax * az, redbuf, t);
  float myy = block_sum(ay * ay, redbuf, t);
  float myz = block_sum(ay * az, redbuf, t);
  float mzz = block_sum(az * az, redbuf, t);
  float c0x = block_sum(ax * p2, redbuf, t);
  float c0y = block_sum(ay * p2, redbuf, t);
  float c0z = block_sum(az * p2, redbuf, t);
  __syncthreads();
  float det = mxx * (myy * mzz - myz * myz) - mxy * (mxy * mzz - myz * mxz) + mxz * (mxy * myz - myy * mxz);
  float idet = 1.f / det;
  float i00 = (myy * mzz - myz * myz) * idet;
  float i01 = (mxz * myz - mxy * mzz) * idet;
  float i02 = (mxy * myz - mxz * myy) * idet;
  float i11 = (mxx * mzz - mxz * mxz) * idet;
  float i12 = (mxy * mxz - mxx * myz) * idet;
  float i22 = (mxx * myy - mxy * mxy) * idet;
  int il = t >> 2, ks = t & 3;
  int i = ic * 64 + il;
  const float* rrow = R2 + ((size_t)(b * 256 + i)) * 256;
  float r0 = 0.f, r1 = 0.f, r2 = 0.f;
  #pragma unroll
  for (int kk = 0; kk < 16; ++kk) {
    int kb = ks * 64 + kk * 4;
    f32x4 rv = *(const f32x4*)(rrow + kb);
    r0 += Ax[kb] * rv.x + Ax[kb + 1] * rv.y + Ax[kb + 2] * rv.z + Ax[kb + 3] * rv.w;
    r1 += Ay[kb] * rv.x + Ay[kb + 1] * rv.y + Ay[kb + 2] * rv.z + Ay[kb + 3] * rv.w;
    r2 += Az[kb] * rv.x + Az[kb + 1] * rv.y + Az[kb + 2] * rv.z + Az[kb + 3] * rv.w;
  }
  r0 += __shfl_xor(r0, 1); r0 += __shfl_xor(r0, 2);
  r1 += __shfl_xor(r1, 1); r1 += __shfl_xor(r1, 2);
  r2 += __shfl_xor(r2, 1); r2 += __shfl_xor(r2, 2);
  if (ks == 0) {
    float hx = c0x - r0, hy = c0y - r1, hz = c0z - r2;
    float x0 = i00 * hx + i01 * hy + i02 * hz;
    float x1 = i01 * hx + i11 * hy + i12 * hz;
    float x2 = i02 * hx + i12 * hy + i22 * hz;
    out[(size_t)(b * 4 + 0) * 256 + i] = x0 - act_pts[(size_t)(b * 3 + 0) * 256 + i];
    out[(size_t)(b * 4 + 1) * 256 + i] = x1 - act_pts[(size_t)(b * 3 + 1) * 256 + i];
    out[(size_t)(b * 4 + 2) * 256 + i] = x2 - act_pts[(size_t)(b * 3 + 2) * 256 + i];
  }
}

extern "C" void kernel_launch(void* const* d_in, const int* in_sizes, int n_in,
                              void* d_out, int out_size, void* d_ws, size_t ws_size,
                              hipStream_t stream)
{
  const float* act_emb = (const float*)d_in[0];
  const float* anc_emb = (const float*)d_in[1];
  const float* act_pts = (const float*)d_in[2];
  const float* anc_pts = (const float*)d_in[3];
  const float* W1  = (const float*)d_in[4];
  const float* b1  = (const float*)d_in[5];
  const float* W2  = (const float*)d_in[6];
  const float* b2  = (const float*)d_in[7];
  const float* W3  = (const float*)d_in[8];
  const float* b3  = (const float*)d_in[9];
  const float* pnW0 = (const float*)d_in[10];
  const float* pnB0 = (const float*)d_in[11];
  const float* pnW1 = (const float*)d_in[12];
  const float* pnB1 = (const float*)d_in[13];
  const float* pnW2 = (const float*)d_in[14];
  const float* pnB2 = (const float*)d_in[15];
  const float* pnW3 = (const float*)d_in[16];
  const float* pnB3 = (const float*)d_in[17];
  const float* pnW4 = (const float*)d_in[18];
  const float* pnB4 = (const float*)d_in[19];
  const float* headW = (const float*)d_in[20];
  char* ws = (char*)d_ws;
  __hip_bfloat16* embT  = (__hip_bfloat16*)(ws + OFF_EMBT);
  __hip_bfloat16* W1T   = (__hip_bfloat16*)(ws + OFF_W1T);
  unsigned short* W2Tsw = (unsigned short*)(ws + OFF_W2TSW);
  unsigned short* W0bf  = (unsigned short*)(ws + OFF_W0BF);
  _Float16* ha_ws = (_Float16*)(ws + OFF_HA);
  float* R2ws  = (float*)(ws + OFF_R2);
  float* outp  = (float*)d_out;

  ka_prep<<<246, 256, 0, stream>>>(act_emb, anc_emb, W1, W2, pnW0, ws);
  k1_ha<<<352, 256, 0, stream>>>(embT, W1T, b1, ha_ws, W0bf,
                                 pnW1, pnW2, pnW3, pnW4, pnB0, pnB1, pnB2, pnB3, pnB4,
                                 headW, outp);
  k2_main<<<2048, 256, 0, stream>>>(ha_ws, W2Tsw, b2, W3, b3, R2ws);
  k3_solve<<<8, 256, 0, stream>>>(anc_pts, act_pts, R2ws, outp);
}

// Round 5
// 168.209 us; speedup vs baseline: 2.2039x; 1.0532x over previous
//
#include <hip/hip_runtime.h>
#include <hip/hip_bf16.h>
#include <hip/hip_fp16.h>

typedef float f32x4 __attribute__((ext_vector_type(4)));
typedef short s16x8 __attribute__((ext_vector_type(8)));
typedef _Float16 f16x8 __attribute__((ext_vector_type(8)));

// ---- workspace layout (bytes) ----
#define OFF_EMBT   0u         // bf16 [2][2][256][512]  (embT[b][A/B][n][e])
#define OFF_W1T    1048576u   // bf16 [600][512]        (W1T[c][e])
#define OFF_W2TSW  1662976u   // f16 swizzled [7][10][64][8]  (B-fragments of W2, padded 112x320)
#define OFF_W0BF   1734656u   // bf16 [64][512]
#define OFF_HA     1800192u   // f16 [2][4][256][320]  0=hAa+b1 1=hAb+b1 2=hBa 3=hBb
#define OFF_R2     3110912u   // f32 [2][256][256]
#define WS_TOTAL   3635200u

__device__ __forceinline__ int pack_bf2(float a, float b) {
  __hip_bfloat162 h = __float22bfloat162_rn(make_float2(a, b));
  int r; __builtin_memcpy(&r, &h, 4); return r;
}
__device__ __forceinline__ unsigned pack_f16_2(float a, float b) {
  __half2 h = __float22half2_rn(make_float2(a, b));
  unsigned r; __builtin_memcpy(&r, &h, 4); return r;
}
__device__ __forceinline__ unsigned short bf16u(float f) {
  __hip_bfloat16 h = __float2bfloat16(f);
  unsigned short u; __builtin_memcpy(&u, &h, 2); return u;
}
__device__ __forceinline__ s16x8 i4_to_s8(int a, int b, int c, int d) {
  union { int i[4]; s16x8 s; } u;
  u.i[0] = a; u.i[1] = b; u.i[2] = c; u.i[3] = d; return u.s;
}

// ================= KA: pack / transpose prep =================
__global__ __launch_bounds__(256) void ka_prep(
    const float* __restrict__ act_emb, const float* __restrict__ anc_emb,
    const float* __restrict__ W1, const float* __restrict__ W2,
    const float* __restrict__ W0pn, char* __restrict__ ws)
{
  __hip_bfloat16* embT  = (__hip_bfloat16*)(ws + OFF_EMBT);
  __hip_bfloat16* W1T   = (__hip_bfloat16*)(ws + OFF_W1T);
  unsigned short* W2Tsw = (unsigned short*)(ws + OFF_W2TSW);
  unsigned short* W0bf  = (unsigned short*)(ws + OFF_W0BF);
  __shared__ float tile[64][65];
  int blk = blockIdx.x, t = threadIdx.x;
  if (blk < 128) {
    int b = blk >> 6, emb = (blk >> 5) & 1, ntile = (blk >> 3) & 3, etile = blk & 7;
    const float* src = emb ? anc_emb : act_emb;
    int e0 = etile * 64, n0 = ntile * 64;
    int rr = t >> 6, cc = t & 63;
    #pragma unroll
    for (int it2 = 0; it2 < 16; ++it2) {
      int e_l = rr * 16 + it2;
      tile[e_l][cc] = src[(size_t)(b * 512 + e0 + e_l) * 256 + n0 + cc];
    }
    __syncthreads();
    int n_l = t >> 2, eq = t & 3;
    unsigned int* dst = (unsigned int*)(embT + ((size_t)((b * 2 + emb) * 256 + n0 + n_l)) * 512 + e0 + eq * 16);
    #pragma unroll
    for (int kk = 0; kk < 8; ++kk)
      dst[kk] = (unsigned)pack_bf2(tile[eq * 16 + 2 * kk][n_l], tile[eq * 16 + 2 * kk + 1][n_l]);
  } else if (blk < 208) {
    int id = blk - 128;
    int half = id / 40; int rem = id % 40; int et = rem / 5; int ct = rem % 5;
    int e0 = et * 64, c0 = ct * 64;
    int rr = t >> 6, cc = t & 63;
    #pragma unroll
    for (int it2 = 0; it2 < 16; ++it2) {
      int e_l = rr * 16 + it2;
      int c = c0 + cc;
      tile[e_l][cc] = (c < 300) ? W1[(size_t)(half * 512 + e0 + e_l) * 300 + c] : 0.f;
    }
    __syncthreads();
    int c_l = t >> 2, eq = t & 3;
    if (c0 + c_l < 300) {
      unsigned int* dst = (unsigned int*)(W1T + ((size_t)(half * 300 + c0 + c_l)) * 512 + e0 + eq * 16);
      #pragma unroll
      for (int kk = 0; kk < 8; ++kk)
        dst[kk] = (unsigned)pack_bf2(tile[eq * 16 + 2 * kk][c_l], tile[eq * 16 + 2 * kk + 1][c_l]);
    }
  } else if (blk < 226) {
    // W2 (f16) swizzled into B-fragment order: idx = (nt*10+ks)*64 + lane
    int idx = (blk - 208) * 256 + t;
    if (idx < 4480) {
      int nt = idx / 640; int rem = idx - nt * 640; int ks = rem >> 6; int lane = rem & 63;
      int n = nt * 16 + (lane & 15);
      int kb = ks * 32 + (lane >> 4) * 8;
      unsigned int q[4];
      #pragma unroll
      for (int jj = 0; jj < 4; ++jj) {
        int k0 = kb + jj * 2, k1 = kb + jj * 2 + 1;
        float f0 = (n < 100 && k0 < 300) ? W2[(size_t)k0 * 100 + n] : 0.f;
        float f1 = (n < 100 && k1 < 300) ? W2[(size_t)k1 * 100 + n] : 0.f;
        q[jj] = pack_f16_2(f0, f1);
      }
      ((uint4*)W2Tsw)[idx] = make_uint4(q[0], q[1], q[2], q[3]);
    }
  } else if (blk < 242) {
    int idx = (blk - 226) * 256 + t;
    const float* s = W0pn + (size_t)idx * 8;
    ((uint4*)W0bf)[idx] = make_uint4(
        (unsigned)pack_bf2(s[0], s[1]), (unsigned)pack_bf2(s[2], s[3]),
        (unsigned)pack_bf2(s[4], s[5]), (unsigned)pack_bf2(s[6], s[7]));
  } else {
    // zero K-pad columns [300,320) of ha_ws (f16): 2048 rows x 20 f16
    int idx = (blk - 242) * 256 + t;  // [0,1024)
    _Float16* ha = (_Float16*)(ws + OFF_HA);
    #pragma unroll
    for (int rr = 0; rr < 2; ++rr) {
      int row = idx * 2 + rr;
      unsigned* p = (unsigned*)(ha + (size_t)row * 320 + 300);
      #pragma unroll
      for (int q2 = 0; q2 < 10; ++q2) p[q2] = 0u;
    }
  }
}

// ================= PointNet layer helper (runs inside k1 pn-blocks) ====
template<int K, int NT>
__device__ __forceinline__ void pn_layer(unsigned short* xb, const float* __restrict__ W,
                                         const float* __restrict__ bias, int wv, int l, int g)
{
  constexpr int NN = NT / 4;
  f32x4 z = {0.f, 0.f, 0.f, 0.f};
  f32x4 acc[NN];
  #pragma unroll
  for (int nn = 0; nn < NN; ++nn) acc[nn] = z;
  #pragma unroll
  for (int nn = 0; nn < NN; ++nn) {
    int o = (wv + nn * 4) * 16 + l;
    const float* wr0 = W + (size_t)o * K;
    #pragma unroll
    for (int ks = 0; ks < K / 32; ++ks) {
      int koff = ks * 32 + g * 8;
      f32x4 wa = *(const f32x4*)(wr0 + koff);
      f32x4 wb = *(const f32x4*)(wr0 + koff + 4);
      s16x8 bfr = i4_to_s8(pack_bf2(wa.x, wa.y), pack_bf2(wa.z, wa.w),
                           pack_bf2(wb.x, wb.y), pack_bf2(wb.z, wb.w));
      s16x8 a0 = *(const s16x8*)(xb + (size_t)l * 520 + koff);
      acc[nn] = __builtin_amdgcn_mfma_f32_16x16x32_bf16(a0, bfr, acc[nn], 0, 0, 0);
    }
  }
  __syncthreads();
  #pragma unroll
  for (int nn = 0; nn < NN; ++nn) {
    int chan = (wv + nn * 4) * 16 + l;
    float bv = bias[chan];
    #pragma unroll
    for (int r = 0; r < 4; ++r)
      xb[(size_t)(g * 4 + r) * 520 + chan] = bf16u(fmaxf(acc[nn][r] + bv, 0.f));
  }
  __syncthreads();
}

// ================= K1: hA GEMMs (blocks 0..319) + PointNet (320..351) ===
__global__ __launch_bounds__(256) void k1_ha(
    const __hip_bfloat16* __restrict__ embT, const __hip_bfloat16* __restrict__ W1T,
    const float* __restrict__ b1, _Float16* __restrict__ ha_ws,
    const unsigned short* __restrict__ W0bf,
    const float* __restrict__ pnW1, const float* __restrict__ pnW2,
    const float* __restrict__ pnW3, const float* __restrict__ pnW4,
    const float* __restrict__ pnB0, const float* __restrict__ pnB1,
    const float* __restrict__ pnB2, const float* __restrict__ pnB3,
    const float* __restrict__ pnB4,
    const float* __restrict__ headW, float* __restrict__ out)
{
  __shared__ unsigned short xbuf[16 * 520];
  int blk = blockIdx.x, t = threadIdx.x;
  int wv = t >> 6, lane = t & 63, l = lane & 15, g = lane >> 4;
  if (blk < 320) {
    int b = blk / 160; int r = blk % 160; int emb = r / 80; r %= 80;
    int mch = r / 5; int nch = r % 5;
    int m0 = mch * 16;
    const unsigned short* Ap = (const unsigned short*)embT +
        ((size_t)((b * 2 + emb) * 256 + m0 + l)) * 512;
    const unsigned short* Wp = (const unsigned short*)W1T;
    f32x4 z = {0.f, 0.f, 0.f, 0.f};
    f32x4 acc[2] = {z, z};
    for (int ks = 0; ks < 16; ++ks) {
      int k0 = ks * 32 + g * 8;
      s16x8 af = *(const s16x8*)(Ap + k0);
      #pragma unroll
      for (int q = 0; q < 2; ++q) {
        int c = nch * 120 + (wv * 2 + q) * 16 + l;
        s16x8 bf = {0, 0, 0, 0, 0, 0, 0, 0};
        if (c < 600) bf = *(const s16x8*)(Wp + (size_t)c * 512 + k0);
        acc[q] = __builtin_amdgcn_mfma_f32_16x16x32_bf16(af, bf, acc[q], 0, 0, 0);
      }
    }
    #pragma unroll
    for (int q = 0; q < 2; ++q) {
      int cl = (wv * 2 + q) * 16 + l;
      int c = nch * 120 + cl;
      if (cl < 120 && c < 600) {
        int half = (c >= 300) ? 1 : 0;
        int cc = c - half * 300;
        float bias = (emb == 0) ? b1[cc] : 0.f;
        _Float16* Dp = ha_ws + ((size_t)((b * 4 + emb * 2 + half) * 256 + m0 + g * 4)) * 320 + cc;
        #pragma unroll
        for (int r2 = 0; r2 < 4; ++r2)
          Dp[(size_t)r2 * 320] = (_Float16)__float2half_rn(acc[q][r2] + bias);
      }
    }
  } else {
    // ---- PointNet: 32 blocks, each 16 points ----
    int pn = blk - 320;
    int b_pn = pn >> 4, n0 = (pn & 15) * 16;
    unsigned short* xb = xbuf;
    {
      const unsigned short* A0 = (const unsigned short*)embT + ((size_t)(b_pn * 2 * 256 + n0)) * 512;
      f32x4 acc0 = {0.f, 0.f, 0.f, 0.f};
      int o = wv * 16 + l;
      const unsigned short* w0r = W0bf + (size_t)o * 512;
      #pragma unroll
      for (int ks = 0; ks < 16; ++ks) {
        int koff = ks * 32 + g * 8;
        s16x8 bfr = *(const s16x8*)(w0r + koff);
        s16x8 a0 = *(const s16x8*)(A0 + (size_t)l * 512 + koff);
        acc0 = __builtin_amdgcn_mfma_f32_16x16x32_bf16(a0, bfr, acc0, 0, 0, 0);
      }
      float bv = pnB0[o];
      #pragma unroll
      for (int r2 = 0; r2 < 4; ++r2)
        xb[(size_t)(g * 4 + r2) * 520 + o] = bf16u(fmaxf(acc0[r2] + bv, 0.f));
      __syncthreads();
    }
    pn_layer<64, 4>(xb, pnW1, pnB1, wv, l, g);
    pn_layer<64, 4>(xb, pnW2, pnB2, wv, l, g);
    pn_layer<64, 8>(xb, pnW3, pnB3, wv, l, g);
    pn_layer<128, 32>(xb, pnW4, pnB4, wv, l, g);
    {
      int p_l = t >> 4, os = t & 15;
      const unsigned short* row = xb + (size_t)p_l * 520 + os * 32;
      float s = 0.f;
      #pragma unroll
      for (int c = 0; c < 32; ++c) {
        unsigned int u = ((unsigned int)row[c]) << 16;
        float xv; __builtin_memcpy(&xv, &u, 4);
        s += xv * headW[os * 32 + c];
      }
      s += __shfl_xor(s, 1); s += __shfl_xor(s, 2);
      s += __shfl_xor(s, 4); s += __shfl_xor(s, 8);
      if (os == 0) out[(size_t)(b_pn * 4 + 3) * 256 + n0 + p_l] = s;
    }
  }
}

// ================= K2: pairwise MLP tail (f16, 512-thread blocks) =======
// 1024 blocks x 512 thr: b(2) x it(16) x jt(32). Tile = 16 i x 8 j;
// wave w owns j = jt*8 + w.  One 71.6KB W2 LDS copy serves 8 waves ->
// 2 blocks/CU = 143KB LDS, 4 waves/SIMD for latency hiding.
// __launch_bounds__(512,4): cap 128 regs/wave (acc=56 + working ~60).
__global__ __launch_bounds__(512, 4) void k2_main(
    const _Float16* __restrict__ ha_ws, const unsigned short* __restrict__ W2Tsw,
    const float* __restrict__ b2g, const float* __restrict__ W3g, const float* __restrict__ b3g,
    float* __restrict__ R2)
{
  __shared__ int4 w2s[4480];  // 71680 B : all 7 nt
  int blk = blockIdx.x, t = threadIdx.x;
  int wv = t >> 6, lane = t & 63, l = lane & 15, g = lane >> 4;
  int b = blk >> 9, it = (blk >> 5) & 15, jt = blk & 31;
  int i0 = it * 16, j = jt * 8 + wv;
  // stage all W2 fragments into LDS
  {
    const int4* w2g = (const int4*)W2Tsw;
    for (int u = t; u < 4480; u += 512) w2s[u] = w2g[u];
  }
  __syncthreads();
  const _Float16* hap0 = ha_ws + ((size_t)((b * 4 + 0) * 256 + i0 + l)) * 320;  // hAa+b1
  const _Float16* hap1 = ha_ws + ((size_t)((b * 4 + 1) * 256 + i0 + l)) * 320;  // hAb+b1
  const _Float16* hbp0 = ha_ws + ((size_t)((b * 4 + 3) * 256 + j)) * 320;       // hBb (rep0)
  const _Float16* hbp1 = ha_ws + ((size_t)((b * 4 + 2) * 256 + j)) * 320;       // hBa (rep1)
  f32x4 z = {0.f, 0.f, 0.f, 0.f};
  f32x4 acc0[7], acc1[7];
  #pragma unroll
  for (int nt = 0; nt < 7; ++nt) { acc0[nt] = z; acc1[nt] = z; }
  const f16x8 zf = {0, 0, 0, 0, 0, 0, 0, 0};
  #pragma unroll
  for (int ks = 0; ks < 10; ++ks) {
    int koff = ks * 32 + g * 8;
    f16x8 ha0 = *(const f16x8*)(hap0 + koff);
    f16x8 hb0 = *(const f16x8*)(hbp0 + koff);
    f16x8 ha1 = *(const f16x8*)(hap1 + koff);
    f16x8 hb1 = *(const f16x8*)(hbp1 + koff);
    f16x8 af0 = __builtin_elementwise_max(ha0 + hb0, zf);
    f16x8 af1 = __builtin_elementwise_max(ha1 + hb1, zf);
    #pragma unroll
    for (int nt = 0; nt < 7; ++nt) {
      f16x8 bf = *(const f16x8*)&w2s[(nt * 10 + ks) * 64 + lane];
      acc0[nt] = __builtin_amdgcn_mfma_f32_16x16x32_f16(af0, bf, acc0[nt], 0, 0, 0);
      acc1[nt] = __builtin_amdgcn_mfma_f32_16x16x32_f16(af1, bf, acc1[nt], 0, 0, 0);
    }
  }
  // epilogue: relu(h2)+dot(W3), reduce over 16-lane col group, softplus
  {
    float w3v[7], b2v[7];
    #pragma unroll
    for (int nt = 0; nt < 7; ++nt) {
      int n = nt * 16 + l;
      w3v[nt] = (n < 100) ? W3g[n] : 0.f;
      b2v[nt] = (n < 100) ? b2g[n] : 0.f;
    }
    float b3 = b3g[0];
    #pragma unroll
    for (int r = 0; r < 4; ++r) {
      float pv = 0.f;
      #pragma unroll
      for (int nt = 0; nt < 7; ++nt) {
        pv += fmaxf(acc0[nt][r] + b2v[nt], 0.f) * w3v[nt];
        pv += fmaxf(acc1[nt][r] + b2v[nt], 0.f) * w3v[nt];
      }
      pv += __shfl_xor(pv, 1);
      pv += __shfl_xor(pv, 2);
      pv += __shfl_xor(pv, 4);
      pv += __shfl_xor(pv, 8);
      float S = 0.5f * pv + b3;
      float Rr = (S > 20.f) ? S : log1pf(expf(S));
      if (l == 0)
        R2[((size_t)(b * 256 + i0 + g * 4 + r)) * 256 + j] = Rr * Rr;
    }
  }
}

// ================= K3: multilateration solve =================
__device__ __forceinline__ float block_sum(float v, float* redbuf, int t) {
  #pragma unroll
  for (int m = 1; m < 64; m <<= 1) v += __shfl_xor(v, m);
  __syncthreads();
  if ((t & 63) == 0) redbuf[t >> 6] = v;
  __syncthreads();
  return redbuf[0] + redbuf[1] + redbuf[2] + redbuf[3];
}

__global__ __launch_bounds__(256) void k3_solve(
    const float* __restrict__ anc_pts, const float* __restrict__ act_pts,
    const float* __restrict__ R2, float* __restrict__ out)
{
  __shared__ float Ax[256], Ay[256], Az[256];
  __shared__ float redbuf[4];
  int blk = blockIdx.x, t = threadIdx.x;
  int b = blk >> 2, ic = blk & 3;
  int k = t;
  float px = anc_pts[(size_t)(b * 3 + 0) * 256 + k];
  float py = anc_pts[(size_t)(b * 3 + 1) * 256 + k];
  float pz = anc_pts[(size_t)(b * 3 + 2) * 256 + k];
  float qx = block_sum(px, redbuf, t) * (1.f / 256.f);
  float qy = block_sum(py, redbuf, t) * (1.f / 256.f);
  float qz = block_sum(pz, redbuf, t) * (1.f / 256.f);
  float ax = 2.f * (px - qx), ay = 2.f * (py - qy), az = 2.f * (pz - qz);
  float p2 = px * px + py * py + pz * pz;
  Ax[k] = ax; Ay[k] = ay; Az[k] = az;
  float mxx = block_sum(ax * ax, redbuf, t);
  float mxy = block_sum(ax * ay, redbuf, t);
  float mxz = block_sum(ax * az, redbuf, t);
  float myy = block_sum(ay * ay, redbuf, t);
  float myz = block_sum(ay * az, redbuf, t);
  float mzz = block_sum(az * az, redbuf, t);
  float c0x = block_sum(ax * p2, redbuf, t);
  float c0y = block_sum(ay * p2, redbuf, t);
  float c0z = block_sum(az * p2, redbuf, t);
  __syncthreads();
  float det = mxx * (myy * mzz - myz * myz) - mxy * (mxy * mzz - myz * mxz) + mxz * (mxy * myz - myy * mxz);
  float idet = 1.f / det;
  float i00 = (myy * mzz - myz * myz) * idet;
  float i01 = (mxz * myz - mxy * mzz) * idet;
  float i02 = (mxy * myz - mxz * myy) * idet;
  float i11 = (mxx * mzz - mxz * mxz) * idet;
  float i12 = (mxy * mxz - mxx * myz) * idet;
  float i22 = (mxx * myy - mxy * mxy) * idet;
  int il = t >> 2, ks = t & 3;
  int i = ic * 64 + il;
  const float* rrow = R2 + ((size_t)(b * 256 + i)) * 256;
  float r0 = 0.f, r1 = 0.f, r2 = 0.f;
  #pragma unroll
  for (int kk = 0; kk < 16; ++kk) {
    int kb = ks * 64 + kk * 4;
    f32x4 rv = *(const f32x4*)(rrow + kb);
    r0 += Ax[kb] * rv.x + Ax[kb + 1] * rv.y + Ax[kb + 2] * rv.z + Ax[kb + 3] * rv.w;
    r1 += Ay[kb] * rv.x + Ay[kb + 1] * rv.y + Ay[kb + 2] * rv.z + Ay[kb + 3] * rv.w;
    r2 += Az[kb] * rv.x + Az[kb + 1] * rv.y + Az[kb + 2] * rv.z + Az[kb + 3] * rv.w;
  }
  r0 += __shfl_xor(r0, 1); r0 += __shfl_xor(r0, 2);
  r1 += __shfl_xor(r1, 1); r1 += __shfl_xor(r1, 2);
  r2 += __shfl_xor(r2, 1); r2 += __shfl_xor(r2, 2);
  if (ks == 0) {
    float hx = c0x - r0, hy = c0y - r1, hz = c0z - r2;
    float x0 = i00 * hx + i01 * hy + i02 * hz;
    float x1 = i01 * hx + i11 * hy + i12 * hz;
    float x2 = i02 * hx + i12 * hy + i22 * hz;
    out[(size_t)(b * 4 + 0) * 256 + i] = x0 - act_pts[(size_t)(b * 3 + 0) * 256 + i];
    out[(size_t)(b * 4 + 1) * 256 + i] = x1 - act_pts[(size_t)(b * 3 + 1) * 256 + i];
    out[(size_t)(b * 4 + 2) * 256 + i] = x2 - act_pts[(size_t)(b * 3 + 2) * 256 + i];
  }
}

extern "C" void kernel_launch(void* const* d_in, const int* in_sizes, int n_in,
                              void* d_out, int out_size, void* d_ws, size_t ws_size,
                              hipStream_t stream)
{
  const float* act_emb = (const float*)d_in[0];
  const float* anc_emb = (const float*)d_in[1];
  const float* act_pts = (const float*)d_in[2];
  const float* anc_pts = (const float*)d_in[3];
  const float* W1  = (const float*)d_in[4];
  const float* b1  = (const float*)d_in[5];
  const float* W2  = (const float*)d_in[6];
  const float* b2  = (const float*)d_in[7];
  const float* W3  = (const float*)d_in[8];
  const float* b3  = (const float*)d_in[9];
  const float* pnW0 = (const float*)d_in[10];
  const float* pnB0 = (const float*)d_in[11];
  const float* pnW1 = (const float*)d_in[12];
  const float* pnB1 = (const float*)d_in[13];
  const float* pnW2 = (const float*)d_in[14];
  const float* pnB2 = (const float*)d_in[15];
  const float* pnW3 = (const float*)d_in[16];
  const float* pnB3 = (const float*)d_in[17];
  const float* pnW4 = (const float*)d_in[18];
  const float* pnB4 = (const float*)d_in[19];
  const float* headW = (const float*)d_in[20];
  char* ws = (char*)d_ws;
  __hip_bfloat16* embT  = (__hip_bfloat16*)(ws + OFF_EMBT);
  __hip_bfloat16* W1T   = (__hip_bfloat16*)(ws + OFF_W1T);
  unsigned short* W2Tsw = (unsigned short*)(ws + OFF_W2TSW);
  unsigned short* W0bf  = (unsigned short*)(ws + OFF_W0BF);
  _Float16* ha_ws = (_Float16*)(ws + OFF_HA);
  float* R2ws  = (float*)(ws + OFF_R2);
  float* outp  = (float*)d_out;

  ka_prep<<<246, 256, 0, stream>>>(act_emb, anc_emb, W1, W2, pnW0, ws);
  k1_ha<<<352, 256, 0, stream>>>(embT, W1T, b1, ha_ws, W0bf,
                                 pnW1, pnW2, pnW3, pnW4, pnB0, pnB1, pnB2, pnB3, pnB4,
                                 headW, outp);
  k2_main<<<1024, 512, 0, stream>>>(ha_ws, W2Tsw, b2, W3, b3, R2ws);
  k3_solve<<<8, 256, 0, stream>>>(anc_pts, act_pts, R2ws, outp);
}

// Round 6
// 165.662 us; speedup vs baseline: 2.2378x; 1.0154x over previous
//
#include <hip/hip_runtime.h>
#include <hip/hip_bf16.h>
#include <hip/hip_fp16.h>

typedef float f32x4 __attribute__((ext_vector_type(4)));
typedef short s16x8 __attribute__((ext_vector_type(8)));
typedef _Float16 f16x8 __attribute__((ext_vector_type(8)));

// ---- workspace layout (bytes) ----
#define OFF_EMBT   0u         // bf16 [2][2][256][512]  (embT[b][A/B][n][e])
#define OFF_W1T    1048576u   // bf16 [600][512]        (W1T[c][e])
#define OFF_W2TSW  1662976u   // f16 swizzled [7][10][64][8]  (B-fragments of W2, padded 112x320)
#define OFF_W0BF   1734656u   // bf16 [64][512]
#define OFF_HA     1800192u   // f16 [2][4][256][320]  0=hAa+b1 1=hAb+b1 2=hBa 3=hBb
#define OFF_R2     3110912u   // f32 [2][256][256]
#define WS_TOTAL   3635200u

__device__ __forceinline__ int pack_bf2(float a, float b) {
  __hip_bfloat162 h = __float22bfloat162_rn(make_float2(a, b));
  int r; __builtin_memcpy(&r, &h, 4); return r;
}
__device__ __forceinline__ unsigned pack_f16_2(float a, float b) {
  __half2 h = __float22half2_rn(make_float2(a, b));
  unsigned r; __builtin_memcpy(&r, &h, 4); return r;
}
__device__ __forceinline__ unsigned short bf16u(float f) {
  __hip_bfloat16 h = __float2bfloat16(f);
  unsigned short u; __builtin_memcpy(&u, &h, 2); return u;
}
__device__ __forceinline__ s16x8 i4_to_s8(int a, int b, int c, int d) {
  union { int i[4]; s16x8 s; } u;
  u.i[0] = a; u.i[1] = b; u.i[2] = c; u.i[3] = d; return u.s;
}

// ================= KA: pack / transpose prep =================
__global__ __launch_bounds__(256) void ka_prep(
    const float* __restrict__ act_emb, const float* __restrict__ anc_emb,
    const float* __restrict__ W1, const float* __restrict__ W2,
    const float* __restrict__ W0pn, char* __restrict__ ws)
{
  __hip_bfloat16* embT  = (__hip_bfloat16*)(ws + OFF_EMBT);
  __hip_bfloat16* W1T   = (__hip_bfloat16*)(ws + OFF_W1T);
  unsigned short* W2Tsw = (unsigned short*)(ws + OFF_W2TSW);
  unsigned short* W0bf  = (unsigned short*)(ws + OFF_W0BF);
  __shared__ float tile[64][65];
  int blk = blockIdx.x, t = threadIdx.x;
  if (blk < 128) {
    int b = blk >> 6, emb = (blk >> 5) & 1, ntile = (blk >> 3) & 3, etile = blk & 7;
    const float* src = emb ? anc_emb : act_emb;
    int e0 = etile * 64, n0 = ntile * 64;
    int rr = t >> 6, cc = t & 63;
    #pragma unroll
    for (int it2 = 0; it2 < 16; ++it2) {
      int e_l = rr * 16 + it2;
      tile[e_l][cc] = src[(size_t)(b * 512 + e0 + e_l) * 256 + n0 + cc];
    }
    __syncthreads();
    int n_l = t >> 2, eq = t & 3;
    unsigned int* dst = (unsigned int*)(embT + ((size_t)((b * 2 + emb) * 256 + n0 + n_l)) * 512 + e0 + eq * 16);
    #pragma unroll
    for (int kk = 0; kk < 8; ++kk)
      dst[kk] = (unsigned)pack_bf2(tile[eq * 16 + 2 * kk][n_l], tile[eq * 16 + 2 * kk + 1][n_l]);
  } else if (blk < 208) {
    int id = blk - 128;
    int half = id / 40; int rem = id % 40; int et = rem / 5; int ct = rem % 5;
    int e0 = et * 64, c0 = ct * 64;
    int rr = t >> 6, cc = t & 63;
    #pragma unroll
    for (int it2 = 0; it2 < 16; ++it2) {
      int e_l = rr * 16 + it2;
      int c = c0 + cc;
      tile[e_l][cc] = (c < 300) ? W1[(size_t)(half * 512 + e0 + e_l) * 300 + c] : 0.f;
    }
    __syncthreads();
    int c_l = t >> 2, eq = t & 3;
    if (c0 + c_l < 300) {
      unsigned int* dst = (unsigned int*)(W1T + ((size_t)(half * 300 + c0 + c_l)) * 512 + e0 + eq * 16);
      #pragma unroll
      for (int kk = 0; kk < 8; ++kk)
        dst[kk] = (unsigned)pack_bf2(tile[eq * 16 + 2 * kk][c_l], tile[eq * 16 + 2 * kk + 1][c_l]);
    }
  } else if (blk < 226) {
    // W2 (f16) swizzled into B-fragment order: idx = (nt*10+ks)*64 + lane
    int idx = (blk - 208) * 256 + t;
    if (idx < 4480) {
      int nt = idx / 640; int rem = idx - nt * 640; int ks = rem >> 6; int lane = rem & 63;
      int n = nt * 16 + (lane & 15);
      int kb = ks * 32 + (lane >> 4) * 8;
      unsigned int q[4];
      #pragma unroll
      for (int jj = 0; jj < 4; ++jj) {
        int k0 = kb + jj * 2, k1 = kb + jj * 2 + 1;
        float f0 = (n < 100 && k0 < 300) ? W2[(size_t)k0 * 100 + n] : 0.f;
        float f1 = (n < 100 && k1 < 300) ? W2[(size_t)k1 * 100 + n] : 0.f;
        q[jj] = pack_f16_2(f0, f1);
      }
      ((uint4*)W2Tsw)[idx] = make_uint4(q[0], q[1], q[2], q[3]);
    }
  } else if (blk < 242) {
    int idx = (blk - 226) * 256 + t;
    const float* s = W0pn + (size_t)idx * 8;
    ((uint4*)W0bf)[idx] = make_uint4(
        (unsigned)pack_bf2(s[0], s[1]), (unsigned)pack_bf2(s[2], s[3]),
        (unsigned)pack_bf2(s[4], s[5]), (unsigned)pack_bf2(s[6], s[7]));
  } else {
    // zero K-pad columns [300,320) of ha_ws (f16): 2048 rows x 20 f16
    int idx = (blk - 242) * 256 + t;  // [0,1024)
    _Float16* ha = (_Float16*)(ws + OFF_HA);
    #pragma unroll
    for (int rr = 0; rr < 2; ++rr) {
      int row = idx * 2 + rr;
      unsigned* p = (unsigned*)(ha + (size_t)row * 320 + 300);
      #pragma unroll
      for (int q2 = 0; q2 < 10; ++q2) p[q2] = 0u;
    }
  }
}

// ================= PointNet layer helper (runs inside k1 pn-blocks) ====
template<int K, int NT>
__device__ __forceinline__ void pn_layer(unsigned short* xb, const float* __restrict__ W,
                                         const float* __restrict__ bias, int wv, int l, int g)
{
  constexpr int NN = NT / 4;
  f32x4 z = {0.f, 0.f, 0.f, 0.f};
  f32x4 acc[NN];
  #pragma unroll
  for (int nn = 0; nn < NN; ++nn) acc[nn] = z;
  #pragma unroll
  for (int nn = 0; nn < NN; ++nn) {
    int o = (wv + nn * 4) * 16 + l;
    const float* wr0 = W + (size_t)o * K;
    #pragma unroll
    for (int ks = 0; ks < K / 32; ++ks) {
      int koff = ks * 32 + g * 8;
      f32x4 wa = *(const f32x4*)(wr0 + koff);
      f32x4 wb = *(const f32x4*)(wr0 + koff + 4);
      s16x8 bfr = i4_to_s8(pack_bf2(wa.x, wa.y), pack_bf2(wa.z, wa.w),
                           pack_bf2(wb.x, wb.y), pack_bf2(wb.z, wb.w));
      s16x8 a0 = *(const s16x8*)(xb + (size_t)l * 520 + koff);
      acc[nn] = __builtin_amdgcn_mfma_f32_16x16x32_bf16(a0, bfr, acc[nn], 0, 0, 0);
    }
  }
  __syncthreads();
  #pragma unroll
  for (int nn = 0; nn < NN; ++nn) {
    int chan = (wv + nn * 4) * 16 + l;
    float bv = bias[chan];
    #pragma unroll
    for (int r = 0; r < 4; ++r)
      xb[(size_t)(g * 4 + r) * 520 + chan] = bf16u(fmaxf(acc[nn][r] + bv, 0.f));
  }
  __syncthreads();
}

// ================= K1: hA GEMMs (blocks 0..319) + PointNet (320..351) ===
__global__ __launch_bounds__(256) void k1_ha(
    const __hip_bfloat16* __restrict__ embT, const __hip_bfloat16* __restrict__ W1T,
    const float* __restrict__ b1, _Float16* __restrict__ ha_ws,
    const unsigned short* __restrict__ W0bf,
    const float* __restrict__ pnW1, const float* __restrict__ pnW2,
    const float* __restrict__ pnW3, const float* __restrict__ pnW4,
    const float* __restrict__ pnB0, const float* __restrict__ pnB1,
    const float* __restrict__ pnB2, const float* __restrict__ pnB3,
    const float* __restrict__ pnB4,
    const float* __restrict__ headW, float* __restrict__ out)
{
  __shared__ unsigned short xbuf[16 * 520];
  int blk = blockIdx.x, t = threadIdx.x;
  int wv = t >> 6, lane = t & 63, l = lane & 15, g = lane >> 4;
  if (blk < 320) {
    int b = blk / 160; int r = blk % 160; int emb = r / 80; r %= 80;
    int mch = r / 5; int nch = r % 5;
    int m0 = mch * 16;
    const unsigned short* Ap = (const unsigned short*)embT +
        ((size_t)((b * 2 + emb) * 256 + m0 + l)) * 512;
    const unsigned short* Wp = (const unsigned short*)W1T;
    f32x4 z = {0.f, 0.f, 0.f, 0.f};
    f32x4 acc[2] = {z, z};
    for (int ks = 0; ks < 16; ++ks) {
      int k0 = ks * 32 + g * 8;
      s16x8 af = *(const s16x8*)(Ap + k0);
      #pragma unroll
      for (int q = 0; q < 2; ++q) {
        int c = nch * 120 + (wv * 2 + q) * 16 + l;
        s16x8 bf = {0, 0, 0, 0, 0, 0, 0, 0};
        if (c < 600) bf = *(const s16x8*)(Wp + (size_t)c * 512 + k0);
        acc[q] = __builtin_amdgcn_mfma_f32_16x16x32_bf16(af, bf, acc[q], 0, 0, 0);
      }
    }
    #pragma unroll
    for (int q = 0; q < 2; ++q) {
      int cl = (wv * 2 + q) * 16 + l;
      int c = nch * 120 + cl;
      if (cl < 120 && c < 600) {
        int half = (c >= 300) ? 1 : 0;
        int cc = c - half * 300;
        float bias = (emb == 0) ? b1[cc] : 0.f;
        _Float16* Dp = ha_ws + ((size_t)((b * 4 + emb * 2 + half) * 256 + m0 + g * 4)) * 320 + cc;
        #pragma unroll
        for (int r2 = 0; r2 < 4; ++r2)
          Dp[(size_t)r2 * 320] = (_Float16)__float2half_rn(acc[q][r2] + bias);
      }
    }
  } else {
    // ---- PointNet: 32 blocks, each 16 points ----
    int pn = blk - 320;
    int b_pn = pn >> 4, n0 = (pn & 15) * 16;
    unsigned short* xb = xbuf;
    {
      const unsigned short* A0 = (const unsigned short*)embT + ((size_t)(b_pn * 2 * 256 + n0)) * 512;
      f32x4 acc0 = {0.f, 0.f, 0.f, 0.f};
      int o = wv * 16 + l;
      const unsigned short* w0r = W0bf + (size_t)o * 512;
      #pragma unroll
      for (int ks = 0; ks < 16; ++ks) {
        int koff = ks * 32 + g * 8;
        s16x8 bfr = *(const s16x8*)(w0r + koff);
        s16x8 a0 = *(const s16x8*)(A0 + (size_t)l * 512 + koff);
        acc0 = __builtin_amdgcn_mfma_f32_16x16x32_bf16(a0, bfr, acc0, 0, 0, 0);
      }
      float bv = pnB0[o];
      #pragma unroll
      for (int r2 = 0; r2 < 4; ++r2)
        xb[(size_t)(g * 4 + r2) * 520 + o] = bf16u(fmaxf(acc0[r2] + bv, 0.f));
      __syncthreads();
    }
    pn_layer<64, 4>(xb, pnW1, pnB1, wv, l, g);
    pn_layer<64, 4>(xb, pnW2, pnB2, wv, l, g);
    pn_layer<64, 8>(xb, pnW3, pnB3, wv, l, g);
    pn_layer<128, 32>(xb, pnW4, pnB4, wv, l, g);
    {
      int p_l = t >> 4, os = t & 15;
      const unsigned short* row = xb + (size_t)p_l * 520 + os * 32;
      float s = 0.f;
      #pragma unroll
      for (int c = 0; c < 32; ++c) {
        unsigned int u = ((unsigned int)row[c]) << 16;
        float xv; __builtin_memcpy(&xv, &u, 4);
        s += xv * headW[os * 32 + c];
      }
      s += __shfl_xor(s, 1); s += __shfl_xor(s, 2);
      s += __shfl_xor(s, 4); s += __shfl_xor(s, 8);
      if (os == 0) out[(size_t)(b_pn * 4 + 3) * 256 + n0 + p_l] = s;
    }
  }
}

// ================= K2: pairwise MLP tail (f16, sw-pipelined) ============
// 1024 blocks x 512 thr: b(2) x it(16) x jt(32). Wave owns j = jt*8 + wv.
// #pragma unroll 1 ks-loop with manual 1-deep rotation: next-iter ha/hb
// global loads issue before this iter's 14-MFMA block (~272cyc distance).
// Regs: 56 acc + 32 cur/next + ~20 misc ~ 110 <= 128 cap -> no spill.
__global__ __launch_bounds__(512, 4) void k2_main(
    const _Float16* __restrict__ ha_ws, const unsigned short* __restrict__ W2Tsw,
    const float* __restrict__ b2g, const float* __restrict__ W3g, const float* __restrict__ b3g,
    float* __restrict__ R2)
{
  __shared__ int4 w2s[4480];  // 71680 B : all 7 nt
  int blk = blockIdx.x, t = threadIdx.x;
  int wv = t >> 6, lane = t & 63, l = lane & 15, g = lane >> 4;
  int b = blk >> 9, it = (blk >> 5) & 15, jt = blk & 31;
  int i0 = it * 16, j = jt * 8 + wv;
  // stage all W2 fragments into LDS
  {
    const int4* w2g = (const int4*)W2Tsw;
    for (int u = t; u < 4480; u += 512) w2s[u] = w2g[u];
  }
  // per-lane base pointers (g*8 folded in); ks advances by +32 f16
  const _Float16* hap0 = ha_ws + ((size_t)((b * 4 + 0) * 256 + i0 + l)) * 320 + g * 8;  // hAa+b1
  const _Float16* hap1 = ha_ws + ((size_t)((b * 4 + 1) * 256 + i0 + l)) * 320 + g * 8;  // hAb+b1
  const _Float16* hbp0 = ha_ws + ((size_t)((b * 4 + 3) * 256 + j)) * 320 + g * 8;       // hBb (rep0)
  const _Float16* hbp1 = ha_ws + ((size_t)((b * 4 + 2) * 256 + j)) * 320 + g * 8;       // hBa (rep1)
  // prefetch ks=0 (issues before the barrier; drained by barrier's vmcnt(0))
  f16x8 ha0c = *(const f16x8*)(hap0);
  f16x8 ha1c = *(const f16x8*)(hap1);
  f16x8 hb0c = *(const f16x8*)(hbp0);
  f16x8 hb1c = *(const f16x8*)(hbp1);
  __syncthreads();
  f32x4 z = {0.f, 0.f, 0.f, 0.f};
  f32x4 acc0[7], acc1[7];
  #pragma unroll
  for (int nt = 0; nt < 7; ++nt) { acc0[nt] = z; acc1[nt] = z; }
  const f16x8 zf = {0, 0, 0, 0, 0, 0, 0, 0};
  #pragma unroll 1
  for (int ks = 0; ks < 10; ++ks) {
    f16x8 ha0n, ha1n, hb0n, hb1n;
    if (ks < 9) {
      int noff = (ks + 1) * 32;
      ha0n = *(const f16x8*)(hap0 + noff);
      ha1n = *(const f16x8*)(hap1 + noff);
      hb0n = *(const f16x8*)(hbp0 + noff);
      hb1n = *(const f16x8*)(hbp1 + noff);
    }
    f16x8 af0 = __builtin_elementwise_max(ha0c + hb0c, zf);
    f16x8 af1 = __builtin_elementwise_max(ha1c + hb1c, zf);
    const int4* wp = &w2s[ks * 64 + lane];
    #pragma unroll
    for (int nt = 0; nt < 7; ++nt) {
      f16x8 bf = *(const f16x8*)(wp + nt * 640);
      acc0[nt] = __builtin_amdgcn_mfma_f32_16x16x32_f16(af0, bf, acc0[nt], 0, 0, 0);
      acc1[nt] = __builtin_amdgcn_mfma_f32_16x16x32_f16(af1, bf, acc1[nt], 0, 0, 0);
    }
    ha0c = ha0n; ha1c = ha1n; hb0c = hb0n; hb1c = hb1n;
  }
  // epilogue: relu(h2)+dot(W3), reduce over 16-lane col group, softplus
  {
    float w3v[7], b2v[7];
    #pragma unroll
    for (int nt = 0; nt < 7; ++nt) {
      int n = nt * 16 + l;
      w3v[nt] = (n < 100) ? W3g[n] : 0.f;
      b2v[nt] = (n < 100) ? b2g[n] : 0.f;
    }
    float b3 = b3g[0];
    #pragma unroll
    for (int r = 0; r < 4; ++r) {
      float pv = 0.f;
      #pragma unroll
      for (int nt = 0; nt < 7; ++nt) {
        pv += fmaxf(acc0[nt][r] + b2v[nt], 0.f) * w3v[nt];
        pv += fmaxf(acc1[nt][r] + b2v[nt], 0.f) * w3v[nt];
      }
      pv += __shfl_xor(pv, 1);
      pv += __shfl_xor(pv, 2);
      pv += __shfl_xor(pv, 4);
      pv += __shfl_xor(pv, 8);
      float S = 0.5f * pv + b3;
      float Rr = (S > 20.f) ? S : log1pf(expf(S));
      if (l == 0)
        R2[((size_t)(b * 256 + i0 + g * 4 + r)) * 256 + j] = Rr * Rr;
    }
  }
}

// ================= K3: multilateration solve =================
__device__ __forceinline__ float block_sum(float v, float* redbuf, int t) {
  #pragma unroll
  for (int m = 1; m < 64; m <<= 1) v += __shfl_xor(v, m);
  __syncthreads();
  if ((t & 63) == 0) redbuf[t >> 6] = v;
  __syncthreads();
  return redbuf[0] + redbuf[1] + redbuf[2] + redbuf[3];
}

__global__ __launch_bounds__(256) void k3_solve(
    const float* __restrict__ anc_pts, const float* __restrict__ act_pts,
    const float* __restrict__ R2, float* __restrict__ out)
{
  __shared__ float Ax[256], Ay[256], Az[256];
  __shared__ float redbuf[4];
  int blk = blockIdx.x, t = threadIdx.x;
  int b = blk >> 2, ic = blk & 3;
  int k = t;
  float px = anc_pts[(size_t)(b * 3 + 0) * 256 + k];
  float py = anc_pts[(size_t)(b * 3 + 1) * 256 + k];
  float pz = anc_pts[(size_t)(b * 3 + 2) * 256 + k];
  float qx = block_sum(px, redbuf, t) * (1.f / 256.f);
  float qy = block_sum(py, redbuf, t) * (1.f / 256.f);
  float qz = block_sum(pz, redbuf, t) * (1.f / 256.f);
  float ax = 2.f * (px - qx), ay = 2.f * (py - qy), az = 2.f * (pz - qz);
  float p2 = px * px + py * py + pz * pz;
  Ax[k] = ax; Ay[k] = ay; Az[k] = az;
  float mxx = block_sum(ax * ax, redbuf, t);
  float mxy = block_sum(ax * ay, redbuf, t);
  float mxz = block_sum(ax * az, redbuf, t);
  float myy = block_sum(ay * ay, redbuf, t);
  float myz = block_sum(ay * az, redbuf, t);
  float mzz = block_sum(az * az, redbuf, t);
  float c0x = block_sum(ax * p2, redbuf, t);
  float c0y = block_sum(ay * p2, redbuf, t);
  float c0z = block_sum(az * p2, redbuf, t);
  __syncthreads();
  float det = mxx * (myy * mzz - myz * myz) - mxy * (mxy * mzz - myz * mxz) + mxz * (mxy * myz - myy * mxz);
  float idet = 1.f / det;
  float i00 = (myy * mzz - myz * myz) * idet;
  float i01 = (mxz * myz - mxy * mzz) * idet;
  float i02 = (mxy * myz - mxz * myy) * idet;
  float i11 = (mxx * mzz - mxz * mxz) * idet;
  float i12 = (mxy * mxz - mxx * myz) * idet;
  float i22 = (mxx * myy - mxy * mxy) * idet;
  int il = t >> 2, ks = t & 3;
  int i = ic * 64 + il;
  const float* rrow = R2 + ((size_t)(b * 256 + i)) * 256;
  float r0 = 0.f, r1 = 0.f, r2 = 0.f;
  #pragma unroll
  for (int kk = 0; kk < 16; ++kk) {
    int kb = ks * 64 + kk * 4;
    f32x4 rv = *(const f32x4*)(rrow + kb);
    r0 += Ax[kb] * rv.x + Ax[kb + 1] * rv.y + Ax[kb + 2] * rv.z + Ax[kb + 3] * rv.w;
    r1 += Ay[kb] * rv.x + Ay[kb + 1] * rv.y + Ay[kb + 2] * rv.z + Ay[kb + 3] * rv.w;
    r2 += Az[kb] * rv.x + Az[kb + 1] * rv.y + Az[kb + 2] * rv.z + Az[kb + 3] * rv.w;
  }
  r0 += __shfl_xor(r0, 1); r0 += __shfl_xor(r0, 2);
  r1 += __shfl_xor(r1, 1); r1 += __shfl_xor(r1, 2);
  r2 += __shfl_xor(r2, 1); r2 += __shfl_xor(r2, 2);
  if (ks == 0) {
    float hx = c0x - r0, hy = c0y - r1, hz = c0z - r2;
    float x0 = i00 * hx + i01 * hy + i02 * hz;
    float x1 = i01 * hx + i11 * hy + i12 * hz;
    float x2 = i02 * hx + i12 * hy + i22 * hz;
    out[(size_t)(b * 4 + 0) * 256 + i] = x0 - act_pts[(size_t)(b * 3 + 0) * 256 + i];
    out[(size_t)(b * 4 + 1) * 256 + i] = x1 - act_pts[(size_t)(b * 3 + 1) * 256 + i];
    out[(size_t)(b * 4 + 2) * 256 + i] = x2 - act_pts[(size_t)(b * 3 + 2) * 256 + i];
  }
}

extern "C" void kernel_launch(void* const* d_in, const int* in_sizes, int n_in,
                              void* d_out, int out_size, void* d_ws, size_t ws_size,
                              hipStream_t stream)
{
  const float* act_emb = (const float*)d_in[0];
  const float* anc_emb = (const float*)d_in[1];
  const float* act_pts = (const float*)d_in[2];
  const float* anc_pts = (const float*)d_in[3];
  const float* W1  = (const float*)d_in[4];
  const float* b1  = (const float*)d_in[5];
  const float* W2  = (const float*)d_in[6];
  const float* b2  = (const float*)d_in[7];
  const float* W3  = (const float*)d_in[8];
  const float* b3  = (const float*)d_in[9];
  const float* pnW0 = (const float*)d_in[10];
  const float* pnB0 = (const float*)d_in[11];
  const float* pnW1 = (const float*)d_in[12];
  const float* pnB1 = (const float*)d_in[13];
  const float* pnW2 = (const float*)d_in[14];
  const float* pnB2 = (const float*)d_in[15];
  const float* pnW3 = (const float*)d_in[16];
  const float* pnB3 = (const float*)d_in[17];
  const float* pnW4 = (const float*)d_in[18];
  const float* pnB4 = (const float*)d_in[19];
  const float* headW = (const float*)d_in[20];
  char* ws = (char*)d_ws;
  __hip_bfloat16* embT  = (__hip_bfloat16*)(ws + OFF_EMBT);
  __hip_bfloat16* W1T   = (__hip_bfloat16*)(ws + OFF_W1T);
  unsigned short* W2Tsw = (unsigned short*)(ws + OFF_W2TSW);
  unsigned short* W0bf  = (unsigned short*)(ws + OFF_W0BF);
  _Float16* ha_ws = (_Float16*)(ws + OFF_HA);
  float* R2ws  = (float*)(ws + OFF_R2);
  float* outp  = (float*)d_out;

  ka_prep<<<246, 256, 0, stream>>>(act_emb, anc_emb, W1, W2, pnW0, ws);
  k1_ha<<<352, 256, 0, stream>>>(embT, W1T, b1, ha_ws, W0bf,
                                 pnW1, pnW2, pnW3, pnW4, pnB0, pnB1, pnB2, pnB3, pnB4,
                                 headW, outp);
  k2_main<<<1024, 512, 0, stream>>>(ha_ws, W2Tsw, b2, W3, b3, R2ws);
  k3_solve<<<8, 256, 0, stream>>>(anc_pts, act_pts, R2ws, outp);
}